// Round 1
// baseline (11865.356 us; speedup 1.0000x reference)
//
#include <hip/hip_runtime.h>
#include <hip/hip_bf16.h>

#define T_STEPS 4

__device__ __forceinline__ float hsig(float x) {
    return fminf(fmaxf(0.2f * x + 0.5f, 0.f), 1.f);
}

// ---------------- fused ConvLSTM step (3x3 SAME, NHWC, fp32) ----------------
// One timestep: z = conv(x_t, Wx) + conv(h_{t-1}, Wh) + b; gates i,f,c,o (Keras
// order); c = hsig(zf)*c + hsig(zi)*relu(zc); h = hsig(zo)*relu(c).
// Block: 256 threads = 4 waves. Wave q owns cc quad [ccb+4q, ccb+4q+4) across
// all 4 gates (16 accums * TP px per thread). TP=4: 16x16 px tile (4 px/thr,
// consecutive x); TP=1: 8x8 px tile. Grid: (W/TILE, H/TILE, C/16).
// LDS: input tile [8][TILE+2][TILE+3] (odd row stride -> ~2-way bank aliasing,
// free per m136); weights [9][8][64], compute reads wave-uniform -> broadcast.
template<int TP>
__global__ __launch_bounds__(256)
void lstm_step_kernel(const float* __restrict__ xin,
                      const float* __restrict__ hprev,  // null at t==0
                      float* __restrict__ cst,
                      float* __restrict__ hout,
                      const float* __restrict__ Wx,     // [3][3][Ci][4C]
                      const float* __restrict__ Wh,     // [3][3][C][4C]
                      const float* __restrict__ bias,   // [4C]
                      int H, int Wd, int Ci, int C)
{
    constexpr int KC = 8;
    constexpr int TILE = (TP == 4) ? 16 : 8;
    constexpr int TW = TILE + 2;
    constexpr int TWP = TW + 1;
    __shared__ __align__(16) float ldsIn[KC][TW][TWP];
    __shared__ __align__(16) float ldsW[9][KC][64];

    const int tid  = threadIdx.x;
    const int q    = tid >> 6;                 // wave id = cc quad
    const int lane = tid & 63;
    const int pr = (TP == 4) ? (lane >> 2) : (lane >> 3);
    const int pc = (TP == 4) ? ((lane & 3) * 4) : (lane & 7);

    const int ty0 = blockIdx.y * TILE;
    const int tx0 = blockIdx.x * TILE;
    const int ccb = blockIdx.z * 16;
    const int C4  = C * 4;

    float acc[TP][16];
#pragma unroll
    for (int p = 0; p < TP; ++p)
#pragma unroll
        for (int j = 0; j < 16; ++j) acc[p][j] = 0.f;

    for (int s = 0; s < 2; ++s) {
        const float* __restrict__ src = s ? hprev : xin;
        if (src == nullptr) continue;          // t==0: conv(0,U) == 0
        const int Cs = s ? C : Ci;
        const float* __restrict__ Ws = s ? Wh : Wx;

        for (int c0 = 0; c0 < Cs; c0 += KC) {
            const int kc = min(KC, Cs - c0);
            __syncthreads();                   // protect LDS from prev chunk
            // ---- stage input tile (halo, zero-padded SAME) ----
            for (int pi = tid; pi < TW * TW; pi += 256) {
                const int ry = pi / TW, rx = pi % TW;
                const int iy = ty0 - 1 + ry, ix = tx0 - 1 + rx;
                const bool ok = (iy >= 0) && (iy < H) && (ix >= 0) && (ix < Wd);
                if (ok && kc == KC) {
                    const float4* gp = reinterpret_cast<const float4*>(
                        src + ((size_t)iy * Wd + ix) * Cs + c0);
                    const float4 v0 = gp[0], v1 = gp[1];
                    ldsIn[0][ry][rx] = v0.x; ldsIn[1][ry][rx] = v0.y;
                    ldsIn[2][ry][rx] = v0.z; ldsIn[3][ry][rx] = v0.w;
                    ldsIn[4][ry][rx] = v1.x; ldsIn[5][ry][rx] = v1.y;
                    ldsIn[6][ry][rx] = v1.z; ldsIn[7][ry][rx] = v1.w;
                } else {
                    const float* gp = src + ((size_t)iy * Wd + ix) * Cs + c0;
#pragma unroll
                    for (int k = 0; k < KC; ++k)
                        ldsIn[k][ry][rx] = (ok && k < kc) ? gp[k] : 0.f;
                }
            }
            // ---- stage weights: ldsW[dd][kk][g*16 + m*4 + j] ----
            for (int e = tid; e < 9 * KC * 16; e += 256) {
                const int c4 = e & 15;
                const int kk = (e >> 4) & (KC - 1);
                const int dd = e >> 7;
                float4 v = make_float4(0.f, 0.f, 0.f, 0.f);
                if (kk < kc) {
                    const int g = c4 >> 2, m = c4 & 3;
                    v = *reinterpret_cast<const float4*>(
                        Ws + ((size_t)dd * Cs + c0 + kk) * C4 + g * C + ccb + m * 4);
                }
                *reinterpret_cast<float4*>(&ldsW[dd][kk][c4 * 4]) = v;
            }
            __syncthreads();
            // ---- accumulate ----
#pragma unroll
            for (int dy = 0; dy < 3; ++dy)
#pragma unroll
            for (int dx = 0; dx < 3; ++dx) {
                const int dd = dy * 3 + dx;
#pragma unroll
                for (int kk = 0; kk < KC; ++kk) {
                    const float4 w0 = *reinterpret_cast<const float4*>(&ldsW[dd][kk][ 0 + q * 4]);
                    const float4 w1 = *reinterpret_cast<const float4*>(&ldsW[dd][kk][16 + q * 4]);
                    const float4 w2 = *reinterpret_cast<const float4*>(&ldsW[dd][kk][32 + q * 4]);
                    const float4 w3 = *reinterpret_cast<const float4*>(&ldsW[dd][kk][48 + q * 4]);
#pragma unroll
                    for (int p = 0; p < TP; ++p) {
                        const float a = ldsIn[kk][pr + dy][pc + dx + ((TP == 4) ? p : 0)];
                        acc[p][ 0] = fmaf(a, w0.x, acc[p][ 0]);
                        acc[p][ 1] = fmaf(a, w0.y, acc[p][ 1]);
                        acc[p][ 2] = fmaf(a, w0.z, acc[p][ 2]);
                        acc[p][ 3] = fmaf(a, w0.w, acc[p][ 3]);
                        acc[p][ 4] = fmaf(a, w1.x, acc[p][ 4]);
                        acc[p][ 5] = fmaf(a, w1.y, acc[p][ 5]);
                        acc[p][ 6] = fmaf(a, w1.z, acc[p][ 6]);
                        acc[p][ 7] = fmaf(a, w1.w, acc[p][ 7]);
                        acc[p][ 8] = fmaf(a, w2.x, acc[p][ 8]);
                        acc[p][ 9] = fmaf(a, w2.y, acc[p][ 9]);
                        acc[p][10] = fmaf(a, w2.z, acc[p][10]);
                        acc[p][11] = fmaf(a, w2.w, acc[p][11]);
                        acc[p][12] = fmaf(a, w3.x, acc[p][12]);
                        acc[p][13] = fmaf(a, w3.y, acc[p][13]);
                        acc[p][14] = fmaf(a, w3.z, acc[p][14]);
                        acc[p][15] = fmaf(a, w3.w, acc[p][15]);
                    }
                }
            }
        }
    }

    // ---- gates + state update (acc[p][g*4+j], cc = ccb + 4q + j) ----
    const int cc = ccb + q * 4;
    const float4 bi = *reinterpret_cast<const float4*>(bias + 0 * C + cc);
    const float4 bf = *reinterpret_cast<const float4*>(bias + 1 * C + cc);
    const float4 bc = *reinterpret_cast<const float4*>(bias + 2 * C + cc);
    const float4 bo = *reinterpret_cast<const float4*>(bias + 3 * C + cc);
    const float bia[4] = {bi.x, bi.y, bi.z, bi.w};
    const float bfa[4] = {bf.x, bf.y, bf.z, bf.w};
    const float bca[4] = {bc.x, bc.y, bc.z, bc.w};
    const float boa[4] = {bo.x, bo.y, bo.z, bo.w};
#pragma unroll
    for (int p = 0; p < TP; ++p) {
        const int py = ty0 + pr;
        const int px = tx0 + pc + ((TP == 4) ? p : 0);
        const size_t base = ((size_t)py * Wd + px) * C + cc;
        float4 cold = make_float4(0.f, 0.f, 0.f, 0.f);
        if (hprev) cold = *reinterpret_cast<const float4*>(cst + base);
        const float coa[4] = {cold.x, cold.y, cold.z, cold.w};
        float cn[4], hv[4];
#pragma unroll
        for (int j = 0; j < 4; ++j) {
            const float z_i = acc[p][ 0 + j] + bia[j];
            const float z_f = acc[p][ 4 + j] + bfa[j];
            const float z_c = acc[p][ 8 + j] + bca[j];
            const float z_o = acc[p][12 + j] + boa[j];
            const float ig = hsig(z_i), fg = hsig(z_f), og = hsig(z_o);
            const float cd = fmaxf(z_c, 0.f);
            const float c_ = fg * coa[j] + ig * cd;
            cn[j] = c_;
            hv[j] = og * fmaxf(c_, 0.f);
        }
        *reinterpret_cast<float4*>(cst + base)  = make_float4(cn[0], cn[1], cn[2], cn[3]);
        *reinterpret_cast<float4*>(hout + base) = make_float4(hv[0], hv[1], hv[2], hv[3]);
    }
}

// ---------------- MaxPool (1,2,2), NHWC, float4 over channels ----------------
__global__ void pool_kernel(const float* __restrict__ in, float* __restrict__ out,
                            int H, int Wd, int C, long total4)
{
    const int Ho = H >> 1, Wo = Wd >> 1;
    const int C4 = C >> 2;
    for (long i = (long)blockIdx.x * blockDim.x + threadIdx.x; i < total4;
         i += (long)gridDim.x * blockDim.x) {
        const int c4 = (int)(i % C4);
        long r = i / C4;
        const int x = (int)(r % Wo); r /= Wo;
        const int y = (int)(r % Ho);
        const int t = (int)(r / Ho);
        const float4* a = reinterpret_cast<const float4*>(in) +
                          (((long)t * H + 2 * y) * Wd + 2 * x) * C4 + c4;
        const float4 v00 = a[0], v01 = a[C4];
        const float4 v10 = a[(long)Wd * C4], v11 = a[(long)Wd * C4 + C4];
        float4 o;
        o.x = fmaxf(fmaxf(v00.x, v01.x), fmaxf(v10.x, v11.x));
        o.y = fmaxf(fmaxf(v00.y, v01.y), fmaxf(v10.y, v11.y));
        o.z = fmaxf(fmaxf(v00.z, v01.z), fmaxf(v10.z, v11.z));
        o.w = fmaxf(fmaxf(v00.w, v01.w), fmaxf(v10.w, v11.w));
        reinterpret_cast<float4*>(out)[i] = o;
    }
}

// ------------- concat([A, up2x2(B)], channel-last), float4 -------------
__global__ void upconcat_kernel(const float* __restrict__ A, const float* __restrict__ B,
                                float* __restrict__ out, int H, int Wd, int C1, int C2,
                                long total4)
{
    const int Co4 = (C1 + C2) >> 2, C14 = C1 >> 2, C24 = C2 >> 2;
    for (long i = (long)blockIdx.x * blockDim.x + threadIdx.x; i < total4;
         i += (long)gridDim.x * blockDim.x) {
        const int c4 = (int)(i % Co4);
        long r = i / Co4;
        const int x = (int)(r % Wd); r /= Wd;
        const int y = (int)(r % H);
        const int t = (int)(r / H);
        float4 v;
        if (c4 < C14)
            v = reinterpret_cast<const float4*>(A)[(((long)t * H + y) * Wd + x) * C14 + c4];
        else
            v = reinterpret_cast<const float4*>(B)[
                (((long)t * (H >> 1) + (y >> 1)) * (Wd >> 1) + (x >> 1)) * C24 + (c4 - C14)];
        reinterpret_cast<float4*>(out)[i] = v;
    }
}

// ------------- final 1x1 ConvLSTM, Cin=32 -> C=1 -------------
__global__ void final_step_kernel(const float* __restrict__ h7, const float* __restrict__ hprev,
                                  float* __restrict__ cst, float* __restrict__ hout,
                                  const float* __restrict__ wout,  // [32][4]
                                  const float* __restrict__ uout,  // [4]
                                  const float* __restrict__ bout,  // [4]
                                  float* __restrict__ dout, int N)
{
    const int i = blockIdx.x * 256 + threadIdx.x;
    if (i >= N) return;
    float z0 = bout[0], z1 = bout[1], z2 = bout[2], z3 = bout[3];
    const float* hp = h7 + (size_t)i * 32;
#pragma unroll
    for (int c = 0; c < 32; c += 4) {
        const float4 h4 = *reinterpret_cast<const float4*>(hp + c);
        const float hv4[4] = {h4.x, h4.y, h4.z, h4.w};
#pragma unroll
        for (int j = 0; j < 4; ++j) {
            z0 += hv4[j] * wout[(c + j) * 4 + 0];
            z1 += hv4[j] * wout[(c + j) * 4 + 1];
            z2 += hv4[j] * wout[(c + j) * 4 + 2];
            z3 += hv4[j] * wout[(c + j) * 4 + 3];
        }
    }
    float hpv = 0.f, cold = 0.f;
    if (hprev) { hpv = hprev[i]; cold = cst[i]; }
    z0 += hpv * uout[0]; z1 += hpv * uout[1]; z2 += hpv * uout[2]; z3 += hpv * uout[3];
    const float ig = hsig(z0), fg = hsig(z1), og = hsig(z3);
    const float cd = fmaxf(z2, 0.f);
    const float cn = fg * cold + ig * cd;
    const float hv = og * fmaxf(cn, 0.f);
    cst[i] = cn; hout[i] = hv;
    if (dout) dout[i] = hv;
}

// ---------------- host orchestration ----------------
static void run_lstm(const float* in, float* out, float* cstate, int H, int Wd,
                     int Ci, int C, const float* Wx, const float* Wh, const float* b,
                     bool varA, hipStream_t stream)
{
    const size_t inS = (size_t)H * Wd * Ci, outS = (size_t)H * Wd * C;
    for (int t = 0; t < T_STEPS; ++t) {
        const float* xin = in + t * inS;
        const float* hp = t ? out + (t - 1) * outS : nullptr;
        float* ho = out + t * outS;
        if (varA) {
            dim3 g(Wd / 16, H / 16, C / 16);
            lstm_step_kernel<4><<<g, 256, 0, stream>>>(xin, hp, cstate, ho, Wx, Wh, b, H, Wd, Ci, C);
        } else {
            dim3 g(Wd / 8, H / 8, C / 16);
            lstm_step_kernel<1><<<g, 256, 0, stream>>>(xin, hp, cstate, ho, Wx, Wh, b, H, Wd, Ci, C);
        }
    }
}

extern "C" void kernel_launch(void* const* d_in, const int* in_sizes, int n_in,
                              void* d_out, int out_size, void* d_ws, size_t ws_size,
                              hipStream_t stream)
{
    (void)in_sizes; (void)n_in; (void)out_size; (void)ws_size;
    const float* x = (const float*)d_in[0];
    auto W = [&](int k) { return (const float*)d_in[k]; };
    char* ws = (char*)d_ws;
    const size_t MiB = 1ull << 20;
    auto f = [&](size_t m) { return (float*)(ws + m * MiB); };

    // Arena (peak 202 MiB), lifetimes hand-checked:
    float* bC1  = f(0);    // [4,256,256,32] 32M, live until m7
    float* bC2  = f(32);   // [4,128,128,64] 16M, live until m6
    float* bC3  = f(48);   // [4,64,64,128]   8M, live until m5
    float* bS1A = f(64);   float* bP1  = f(64);  float* bS2A = f(72);
    float* bP2  = f(64);   float* bS3A = f(68);  float* bP3  = f(64);
    float* bS4A = f(66);   float* bC4  = f(70);  float* bM5  = f(74);   // 24M
    float* bS5A = f(64);   float* bC5  = f(98);  float* bM6  = f(106);  // 48M
    float* bS6A = f(64);   float* bC6  = f(80);  float* bM7  = f(96);   // 96M [96,192)
    float* bS7A = f(0);    float* bC7  = f(32);
    float* bCST = f(192);  // per-layer c state, max 8M
    float* bHF  = f(200);  float* bCF  = f(201); // final-layer h,c (256K each)

    auto pool = [&](const float* in, float* out, int H, int Wd, int C) {
        long total4 = (long)T_STEPS * (H / 2) * (Wd / 2) * (C / 4);
        long nb = (total4 + 255) / 256; if (nb > 4096) nb = 4096;
        pool_kernel<<<dim3((unsigned)nb), 256, 0, stream>>>(in, out, H, Wd, C, total4);
    };
    auto upcat = [&](const float* A, const float* B, float* out, int H, int Wd, int C1, int C2) {
        long total4 = (long)T_STEPS * H * Wd * ((C1 + C2) / 4);
        long nb = (total4 + 255) / 256; if (nb > 8192) nb = 8192;
        upconcat_kernel<<<dim3((unsigned)nb), 256, 0, stream>>>(A, B, out, H, Wd, C1, C2, total4);
    };

    run_lstm(x,    bS1A, bCST, 256, 256,   1,  32, W(1),  W(2),  W(3),  true,  stream);
    run_lstm(bS1A, bC1,  bCST, 256, 256,  32,  32, W(4),  W(5),  W(6),  true,  stream);
    pool(bC1, bP1, 256, 256, 32);
    run_lstm(bP1,  bS2A, bCST, 128, 128,  32,  64, W(7),  W(8),  W(9),  true,  stream);
    run_lstm(bS2A, bC2,  bCST, 128, 128,  64,  64, W(10), W(11), W(12), true,  stream);
    pool(bC2, bP2, 128, 128, 64);
    run_lstm(bP2,  bS3A, bCST,  64,  64,  64, 128, W(13), W(14), W(15), false, stream);
    run_lstm(bS3A, bC3,  bCST,  64,  64, 128, 128, W(16), W(17), W(18), false, stream);
    pool(bC3, bP3, 64, 64, 128);
    run_lstm(bP3,  bS4A, bCST,  32,  32, 128, 256, W(19), W(20), W(21), false, stream);
    run_lstm(bS4A, bC4,  bCST,  32,  32, 256, 256, W(22), W(23), W(24), false, stream);
    upcat(bC3, bC4, bM5, 64, 64, 128, 256);
    run_lstm(bM5,  bS5A, bCST,  64,  64, 384, 128, W(25), W(26), W(27), false, stream);
    run_lstm(bS5A, bC5,  bCST,  64,  64, 128, 128, W(28), W(29), W(30), false, stream);
    upcat(bC2, bC5, bM6, 128, 128, 64, 128);
    run_lstm(bM6,  bS6A, bCST, 128, 128, 192,  64, W(31), W(32), W(33), true,  stream);
    run_lstm(bS6A, bC6,  bCST, 128, 128,  64,  64, W(34), W(35), W(36), true,  stream);
    upcat(bC1, bC6, bM7, 256, 256, 32, 64);
    run_lstm(bM7,  bS7A, bCST, 256, 256,  96,  32, W(37), W(38), W(39), true,  stream);
    run_lstm(bS7A, bC7,  bCST, 256, 256,  32,  32, W(40), W(41), W(42), true,  stream);

    const int N = 256 * 256;
    for (int t = 0; t < T_STEPS; ++t) {
        const float* h7 = bC7 + (size_t)t * N * 32;
        final_step_kernel<<<N / 256, 256, 0, stream>>>(
            h7, t ? bHF : nullptr, bCF, bHF, W(43), W(44), W(45),
            (t == T_STEPS - 1) ? (float*)d_out : nullptr, N);
    }
}

// Round 2
// 3174.265 us; speedup vs baseline: 3.7380x; 3.7380x over previous
//
#include <hip/hip_runtime.h>
#include <hip/hip_bf16.h>

#define T_STEPS 4

typedef __attribute__((ext_vector_type(8))) short short8v;   // 8 x bf16 bits
typedef __attribute__((ext_vector_type(4))) float f32x4;
typedef __attribute__((ext_vector_type(4))) unsigned short us4;

__device__ __forceinline__ float hsig(float x) {
    return fminf(fmaxf(0.2f * x + 0.5f, 0.f), 1.f);
}
__device__ __forceinline__ unsigned short f2bf(float v) {
    __hip_bfloat16 h = __float2bfloat16(v);   // RNE
    unsigned short u; __builtin_memcpy(&u, &h, 2); return u;
}
__device__ __forceinline__ float bf2f(unsigned short u) {
    __hip_bfloat16 h; __builtin_memcpy(&h, &u, 2); return __bfloat162float(h);
}

// ============ fused ConvLSTM timestep via split-bf16 MFMA implicit GEMM ======
// z[p, co'] = sum_{s,dd,ci} src_s[p+dd, ci] * W_s[dd, ci, co'];  co' = c*4+g
// (gate-interleaved so the 4 gates of a channel live in one 16-col group).
// Each fp32 operand split a = a_hi + a_lo (bf16 pair); 3 MFMAs accumulate
// hi*hi + hi*lo + lo*hi in fp32  -> ~1e-5 relative accuracy.
// TILE=16: block = 256 px (16x16), 4 waves * 4 row-frags, BN=64 (4 ngrps).
// TILE=8 : block =  64 px (8x8),   2x2 waves, 2 row-frags x 2 ngrps each.
// LDS: A halo tile (TILE+2)^2 px * 32ci, pitch 40 ush (80B: 16B-aligned,
// bank-spread); hi+lo planes. B: 2 x 8KB double buffer, fragment-ordered.
template<int TILE>
__global__ __launch_bounds__(256, 2)
void lstm_mfma(const float* __restrict__ xin, const float* __restrict__ hprev,
               float* __restrict__ cst, float* __restrict__ hout,
               const unsigned short* __restrict__ BtX,
               const unsigned short* __restrict__ BtH,
               const float* __restrict__ bias,
               int H, int W, int CiR, int CiP, int C)
{
    constexpr int HS = TILE + 2;
    constexpr int PITCH = 40;                    // ushorts per pixel (32+8 pad)
    constexpr int APLANE = HS * HS * PITCH;      // ushorts per plane
    constexpr int NSLOT = HS * HS * 8;           // float4 staging slots
    constexpr int NFM = (TILE == 16) ? 4 : 2;    // m-frags per wave
    constexpr int NN  = (TILE == 16) ? 4 : 2;    // n-grps per wave
    extern __shared__ char smem[];
    unsigned short* ldsA = (unsigned short*)smem;          // [2][APLANE]
    char* ldsB = smem + (size_t)APLANE * 2 * 2;            // 2 x 8192 B

    const int tid = threadIdx.x, w = tid >> 6, lane = tid & 63;
    const int nb = blockIdx.z;
    const int y0 = blockIdx.y * TILE, x0 = blockIdx.x * TILE;
    const int NG = (4 * C) >> 4;
    const int kq = lane >> 4;

    // per-lane A base offset (ushorts, within plane; row-part included)
    int abase;
    if (TILE == 16) abase = (w * 4) * HS * PITCH + (lane & 15) * PITCH + kq * 8;
    else abase = ((w >> 1) * 4 + ((lane >> 3) & 1)) * HS * PITCH + (lane & 7) * PITCH + kq * 8;

    f32x4 acc[NFM][NN];
#pragma unroll
    for (int a = 0; a < NFM; ++a)
#pragma unroll
        for (int b = 0; b < NN; ++b) acc[a][b] = (f32x4)0.f;

    for (int s = 0; s < 2; ++s) {
        if (s == 1 && hprev == nullptr) break;   // t==0: conv(0,U)==0
        const float* __restrict__ src = s ? hprev : xin;
        const int CsR = s ? C : CiR;
        const int CsP = s ? C : CiP;
        const unsigned short* __restrict__ Bt = s ? BtH : BtX;
        const int nch = CsP >> 5;

        for (int ck = 0; ck < nch; ++ck) {
            __syncthreads();                     // protect ldsA/ldsB reuse
            const int ci0 = ck << 5;
            // ---- stage A halo tile (fp32 -> bf16 hi/lo planes) ----
            for (int i = tid; i < NSLOT; i += 256) {
                const int pix = i >> 3, c4 = (i & 7) << 2;
                const int hy = pix / HS, hx = pix - hy * HS;
                const int iy = y0 + hy - 1, ix = x0 + hx - 1;
                float4 v = make_float4(0.f, 0.f, 0.f, 0.f);
                if (iy >= 0 && iy < H && ix >= 0 && ix < W) {
                    const float* gp = src + ((size_t)iy * W + ix) * CsR + ci0 + c4;
                    if (ci0 + c4 + 4 <= CsR) v = *(const float4*)gp;
                    else {
                        const int rem = CsR - ci0 - c4;
                        if (rem > 0) { v.x = gp[0]; if (rem > 1) v.y = gp[1]; if (rem > 2) v.z = gp[2]; }
                    }
                }
                const float f[4] = {v.x, v.y, v.z, v.w};
                us4 hi, lo;
#pragma unroll
                for (int e = 0; e < 4; ++e) {
                    const unsigned short h = f2bf(f[e]);
                    hi[e] = h; lo[e] = f2bf(f[e] - bf2f(h));
                }
                const int off = pix * PITCH + c4;
                *(us4*)(ldsA + off) = hi;
                *(us4*)(ldsA + APLANE + off) = lo;
            }
            // ---- stage B tap 0 ----
            {
                const float4* bs = (const float4*)(Bt + ((size_t)(ck * 9) * NG + nb * 4) * 1024);
                float4* bd = (float4*)ldsB;
                bd[tid] = bs[tid]; bd[tid + 256] = bs[tid + 256];
            }
            __syncthreads();
            // ---- 9 taps ----
#pragma unroll
            for (int dd = 0; dd < 9; ++dd) {
                const int cur = dd & 1;
                float4 pre0, pre1;
                if (dd < 8) {   // prefetch next tap's B to regs
                    const float4* bs = (const float4*)(Bt + ((size_t)(ck * 9 + dd + 1) * NG + nb * 4) * 1024);
                    pre0 = bs[tid]; pre1 = bs[tid + 256];
                }
                const int dy = dd / 3, dx = dd % 3;
                short8v ah[NFM], al[NFM];
#pragma unroll
                for (int fm = 0; fm < NFM; ++fm) {
                    const int ro = (TILE == 16) ? (fm + dy) : (2 * fm + dy);
                    ah[fm] = *(const short8v*)(ldsA + abase + (ro * HS + dx) * PITCH);
                    al[fm] = *(const short8v*)(ldsA + APLANE + abase + (ro * HS + dx) * PITCH);
                }
#pragma unroll
                for (int nn = 0; nn < NN; ++nn) {
                    const int ng = (TILE == 16) ? nn : ((w & 1) * 2 + nn);
                    const unsigned short* bp = (const unsigned short*)ldsB + cur * 4096 + ng * 1024 + lane * 8;
                    const short8v bh = *(const short8v*)(bp);
                    const short8v bl = *(const short8v*)(bp + 512);
#pragma unroll
                    for (int fm = 0; fm < NFM; ++fm) {
                        acc[fm][nn] = __builtin_amdgcn_mfma_f32_16x16x32_bf16(ah[fm], bh, acc[fm][nn], 0, 0, 0);
                        acc[fm][nn] = __builtin_amdgcn_mfma_f32_16x16x32_bf16(ah[fm], bl, acc[fm][nn], 0, 0, 0);
                        acc[fm][nn] = __builtin_amdgcn_mfma_f32_16x16x32_bf16(al[fm], bh, acc[fm][nn], 0, 0, 0);
                    }
                }
                if (dd < 8) {
                    float4* bd = (float4*)(ldsB + (cur ^ 1) * 8192);
                    bd[tid] = pre0; bd[tid + 256] = pre1;
                }
                __syncthreads();
            }
        }
    }

    // ---- epilogue: transpose D frags via LDS, apply gates ----
    __syncthreads();
    float* lds2 = (float*)smem + w * 276;    // 16x17 pad, per-wave scratch
    const int rr = lane & 15, cl = lane >> 4;
#pragma unroll
    for (int nn = 0; nn < NN; ++nn) {
        const int ngl = (TILE == 16) ? nn : ((w & 1) * 2 + nn);
        const int c = nb * 16 + ngl * 4 + cl;           // channel in [0,C)
        float b4[4];
#pragma unroll
        for (int g = 0; g < 4; ++g) b4[g] = bias[g * C + c];
#pragma unroll
        for (int fm = 0; fm < NFM; ++fm) {
            // D layout: lane holds col=lane&15, rows (lane>>4)*4+j
#pragma unroll
            for (int j = 0; j < 4; ++j) lds2[(cl * 4 + j) * 17 + rr] = acc[fm][nn][j];
            float z[4];
#pragma unroll
            for (int g = 0; g < 4; ++g) z[g] = lds2[rr * 17 + cl * 4 + g];
            int py, px;
            if (TILE == 16) { py = y0 + w * 4 + fm; px = x0 + rr; }
            else { py = y0 + (w >> 1) * 4 + 2 * fm + (rr >> 3); px = x0 + (rr & 7); }
            const size_t base = ((size_t)py * W + px) * C + c;
            const float cold = hprev ? cst[base] : 0.f;
            const float zi = z[0] + b4[0], zf = z[1] + b4[1];
            const float zc = z[2] + b4[2], zo = z[3] + b4[3];
            const float cn = hsig(zf) * cold + hsig(zi) * fmaxf(zc, 0.f);
            const float hv = hsig(zo) * fmaxf(cn, 0.f);
            cst[base] = cn; hout[base] = hv;
        }
    }
}

// ===== weight pre-transform: fp32 [3][3][Cs][4C] -> fragment-ordered bf16 =====
// layout: [ck][dd][ngrp][plane(hi/lo)][lane 0..63][8], k = ck*32+(lane>>4)*8+e,
// co' = ngrp*16 + (lane&15) = c*4+g  ->  src co = g*C + c.  ci>=CsR zero-filled.
__global__ void transform_w_kernel(const float* __restrict__ Wsrc,
                                   unsigned short* __restrict__ Bt,
                                   int CsR, int C, int total)
{
    const int i = blockIdx.x * 256 + threadIdx.x;
    if (i >= total) return;
    const int N = 4 * C, NG = N >> 4;
    const int lane = i & 63; int t = i >> 6;
    const int ng = t % NG; t /= NG;
    const int dd = t % 9; const int ck = t / 9;
    const int colp = ng * 16 + (lane & 15);
    const int c = colp >> 2, g = colp & 3, co = g * C + c;
    const int kb = (lane >> 4) * 8;
    short8v hi8, lo8;
#pragma unroll
    for (int e = 0; e < 8; ++e) {
        const int ci = (ck << 5) + kb + e;
        const float v = (ci < CsR) ? Wsrc[(size_t)(dd * CsR + ci) * N + co] : 0.f;
        const unsigned short h = f2bf(v);
        hi8[e] = (short)h; lo8[e] = (short)f2bf(v - bf2f(h));
    }
    const size_t base = ((size_t)(ck * 9 + dd) * NG + ng) * 1024 + lane * 8;
    *(short8v*)(Bt + base) = hi8;
    *(short8v*)(Bt + base + 512) = lo8;
}

// ---------------- MaxPool (1,2,2), NHWC, float4 over channels ----------------
__global__ void pool_kernel(const float* __restrict__ in, float* __restrict__ out,
                            int H, int Wd, int C, long total4)
{
    const int Ho = H >> 1, Wo = Wd >> 1;
    const int C4 = C >> 2;
    for (long i = (long)blockIdx.x * blockDim.x + threadIdx.x; i < total4;
         i += (long)gridDim.x * blockDim.x) {
        const int c4 = (int)(i % C4);
        long r = i / C4;
        const int x = (int)(r % Wo); r /= Wo;
        const int y = (int)(r % Ho);
        const int t = (int)(r / Ho);
        const float4* a = reinterpret_cast<const float4*>(in) +
                          (((long)t * H + 2 * y) * Wd + 2 * x) * C4 + c4;
        const float4 v00 = a[0], v01 = a[C4];
        const float4 v10 = a[(long)Wd * C4], v11 = a[(long)Wd * C4 + C4];
        float4 o;
        o.x = fmaxf(fmaxf(v00.x, v01.x), fmaxf(v10.x, v11.x));
        o.y = fmaxf(fmaxf(v00.y, v01.y), fmaxf(v10.y, v11.y));
        o.z = fmaxf(fmaxf(v00.z, v01.z), fmaxf(v10.z, v11.z));
        o.w = fmaxf(fmaxf(v00.w, v01.w), fmaxf(v10.w, v11.w));
        reinterpret_cast<float4*>(out)[i] = o;
    }
}

// ------------- concat([A, up2x2(B)], channel-last), float4 -------------
__global__ void upconcat_kernel(const float* __restrict__ A, const float* __restrict__ B,
                                float* __restrict__ out, int H, int Wd, int C1, int C2,
                                long total4)
{
    const int Co4 = (C1 + C2) >> 2, C14 = C1 >> 2, C24 = C2 >> 2;
    for (long i = (long)blockIdx.x * blockDim.x + threadIdx.x; i < total4;
         i += (long)gridDim.x * blockDim.x) {
        const int c4 = (int)(i % Co4);
        long r = i / Co4;
        const int x = (int)(r % Wd); r /= Wd;
        const int y = (int)(r % H);
        const int t = (int)(r / H);
        float4 v;
        if (c4 < C14)
            v = reinterpret_cast<const float4*>(A)[(((long)t * H + y) * Wd + x) * C14 + c4];
        else
            v = reinterpret_cast<const float4*>(B)[
                (((long)t * (H >> 1) + (y >> 1)) * (Wd >> 1) + (x >> 1)) * C24 + (c4 - C14)];
        reinterpret_cast<float4*>(out)[i] = v;
    }
}

// ------------- final 1x1 ConvLSTM, Cin=32 -> C=1 -------------
__global__ void final_step_kernel(const float* __restrict__ h7, const float* __restrict__ hprev,
                                  float* __restrict__ cst, float* __restrict__ hout,
                                  const float* __restrict__ wout,  // [32][4]
                                  const float* __restrict__ uout,  // [4]
                                  const float* __restrict__ bout,  // [4]
                                  float* __restrict__ dout, int N)
{
    const int i = blockIdx.x * 256 + threadIdx.x;
    if (i >= N) return;
    float z0 = bout[0], z1 = bout[1], z2 = bout[2], z3 = bout[3];
    const float* hp = h7 + (size_t)i * 32;
#pragma unroll
    for (int c = 0; c < 32; c += 4) {
        const float4 h4 = *reinterpret_cast<const float4*>(hp + c);
        const float hv4[4] = {h4.x, h4.y, h4.z, h4.w};
#pragma unroll
        for (int j = 0; j < 4; ++j) {
            z0 += hv4[j] * wout[(c + j) * 4 + 0];
            z1 += hv4[j] * wout[(c + j) * 4 + 1];
            z2 += hv4[j] * wout[(c + j) * 4 + 2];
            z3 += hv4[j] * wout[(c + j) * 4 + 3];
        }
    }
    float hpv = 0.f, cold = 0.f;
    if (hprev) { hpv = hprev[i]; cold = cst[i]; }
    z0 += hpv * uout[0]; z1 += hpv * uout[1]; z2 += hpv * uout[2]; z3 += hpv * uout[3];
    const float ig = hsig(z0), fg = hsig(z1), og = hsig(z3);
    const float cd = fmaxf(z2, 0.f);
    const float cn = fg * cold + ig * cd;
    const float hv = og * fmaxf(cn, 0.f);
    cst[i] = cn; hout[i] = hv;
    if (dout) dout[i] = hv;
}

// ---------------- host orchestration ----------------
struct LD { int H, W, CiR, CiP, C, tile, wi; };

static void run_layer(const LD& L, const float* in, float* out, float* cstate,
                      const unsigned short* btx, const unsigned short* bth,
                      const float* bias, hipStream_t stream)
{
    const size_t inS = (size_t)L.H * L.W * L.CiR, outS = (size_t)L.H * L.W * L.C;
    const dim3 grid(L.W / L.tile, L.H / L.tile, (4 * L.C) / 64);
    for (int t = 0; t < T_STEPS; ++t) {
        const float* hp = t ? out + (t - 1) * outS : nullptr;
        if (L.tile == 16) {
            const size_t sh = (size_t)18 * 18 * 40 * 2 * 2 + 16384;
            lstm_mfma<16><<<grid, 256, sh, stream>>>(in + t * inS, hp, cstate, out + t * outS,
                                                     btx, bth, bias, L.H, L.W, L.CiR, L.CiP, L.C);
        } else {
            const size_t sh = (size_t)10 * 10 * 40 * 2 * 2 + 16384;
            lstm_mfma<8><<<grid, 256, sh, stream>>>(in + t * inS, hp, cstate, out + t * outS,
                                                    btx, bth, bias, L.H, L.W, L.CiR, L.CiP, L.C);
        }
    }
}

extern "C" void kernel_launch(void* const* d_in, const int* in_sizes, int n_in,
                              void* d_out, int out_size, void* d_ws, size_t ws_size,
                              hipStream_t stream)
{
    (void)in_sizes; (void)n_in; (void)out_size; (void)ws_size;
    const float* x = (const float*)d_in[0];
    auto Wp = [&](int k) { return (const float*)d_in[k]; };
    char* ws = (char*)d_ws;
    const size_t MiB = 1ull << 20;
    auto f = [&](size_t m) { return (float*)(ws + m * MiB); };

    hipFuncSetAttribute((const void*)lstm_mfma<16>,
                        hipFuncAttributeMaxDynamicSharedMemorySize, 69632);
    hipFuncSetAttribute((const void*)lstm_mfma<8>,
                        hipFuncAttributeMaxDynamicSharedMemorySize, 33792);

    // Arena (peak ~237 MiB; lifetimes hand-checked):
    float* bC1  = f(0);    float* bC2  = f(32);  float* bC3  = f(48);
    float* bCST = f(56);   // shared c-state, <= 8 MiB
    float* bHF  = (float*)(ws + 64 * MiB);
    float* bCF  = (float*)(ws + 64 * MiB + 256 * 1024);
    float* bS1A = f(65);   float* bP1  = f(97);  float* bS2A = f(105);
    float* bP2  = f(97);   float* bS3A = f(101); float* bP3  = f(65);
    float* bS4A = f(67);   float* bC4  = f(71);  float* bM5  = f(75);
    float* bS5A = f(99);   float* bC5  = f(65);  float* bM6  = f(73);
    float* bS6A = f(121);  float* bC6  = f(65);  float* bM7  = f(81);
    float* bS7A = f(0);    float* bC7  = f(81);

    static const LD Ls[14] = {
        {256, 256,   1,  32,  32, 16,  1}, {256, 256,  32,  32,  32, 16,  4},
        {128, 128,  32,  32,  64, 16,  7}, {128, 128,  64,  64,  64, 16, 10},
        { 64,  64,  64,  64, 128,  8, 13}, { 64,  64, 128, 128, 128,  8, 16},
        { 32,  32, 128, 128, 256,  8, 19}, { 32,  32, 256, 256, 256,  8, 22},
        { 64,  64, 384, 384, 128,  8, 25}, { 64,  64, 128, 128, 128,  8, 28},
        {128, 128, 192, 192,  64, 16, 31}, {128, 128,  64,  64,  64, 16, 34},
        {256, 256,  96,  96,  32, 16, 37}, {256, 256,  32,  32,  32, 16, 40},
    };

    // ---- weight transforms into Bt arena at [177 MiB, ...) ----
    unsigned short* btx[14]; unsigned short* bth[14];
    {
        size_t cur = 177 * MiB;
        for (int i = 0; i < 14; ++i) {
            const LD& L = Ls[i];
            const int NG = (4 * L.C) >> 4;
            const size_t szx = (size_t)(L.CiP >> 5) * 9 * NG * 2048;  // bytes
            const size_t szh = (size_t)(L.C  >> 5) * 9 * NG * 2048;
            btx[i] = (unsigned short*)(ws + cur); cur += szx;
            bth[i] = (unsigned short*)(ws + cur); cur += szh;
            const int totx = (L.CiP >> 5) * 9 * NG * 64;
            const int toth = (L.C  >> 5) * 9 * NG * 64;
            transform_w_kernel<<<(totx + 255) / 256, 256, 0, stream>>>(
                Wp(L.wi), btx[i], L.CiR, L.C, totx);
            transform_w_kernel<<<(toth + 255) / 256, 256, 0, stream>>>(
                Wp(L.wi + 1), bth[i], L.C, L.C, toth);
        }
    }

    auto pool = [&](const float* in, float* out, int H, int Wd, int C) {
        long total4 = (long)T_STEPS * (H / 2) * (Wd / 2) * (C / 4);
        long nb = (total4 + 255) / 256; if (nb > 4096) nb = 4096;
        pool_kernel<<<dim3((unsigned)nb), 256, 0, stream>>>(in, out, H, Wd, C, total4);
    };
    auto upcat = [&](const float* A, const float* B, float* out, int H, int Wd, int C1, int C2) {
        long total4 = (long)T_STEPS * H * Wd * ((C1 + C2) / 4);
        long nb = (total4 + 255) / 256; if (nb > 8192) nb = 8192;
        upconcat_kernel<<<dim3((unsigned)nb), 256, 0, stream>>>(A, B, out, H, Wd, C1, C2, total4);
    };
    auto run = [&](int i, const float* in, float* out) {
        run_layer(Ls[i], in, out, bCST, btx[i], bth[i], Wp(Ls[i].wi + 2), stream);
    };

    run(0, x, bS1A);        run(1, bS1A, bC1);
    pool(bC1, bP1, 256, 256, 32);
    run(2, bP1, bS2A);      run(3, bS2A, bC2);
    pool(bC2, bP2, 128, 128, 64);
    run(4, bP2, bS3A);      run(5, bS3A, bC3);
    pool(bC3, bP3, 64, 64, 128);
    run(6, bP3, bS4A);      run(7, bS4A, bC4);
    upcat(bC3, bC4, bM5, 64, 64, 128, 256);
    run(8, bM5, bS5A);      run(9, bS5A, bC5);
    upcat(bC2, bC5, bM6, 128, 128, 64, 128);
    run(10, bM6, bS6A);     run(11, bS6A, bC6);
    upcat(bC1, bC6, bM7, 256, 256, 32, 64);
    run(12, bM7, bS7A);     run(13, bS7A, bC7);

    const int N = 256 * 256;
    for (int t = 0; t < T_STEPS; ++t) {
        const float* h7 = bC7 + (size_t)t * N * 32;
        final_step_kernel<<<N / 256, 256, 0, stream>>>(
            h7, t ? bHF : nullptr, bCF, bHF, Wp(43), Wp(44), Wp(45),
            (t == T_STEPS - 1) ? (float*)d_out : nullptr, N);
    }
}

// Round 3
// 2926.837 us; speedup vs baseline: 4.0540x; 1.0845x over previous
//
#include <hip/hip_runtime.h>
#include <hip/hip_bf16.h>

#define T_STEPS 4

typedef __attribute__((ext_vector_type(8))) short short8v;   // 8 x bf16 bits
typedef __attribute__((ext_vector_type(4))) float f32x4;
typedef __attribute__((ext_vector_type(4))) unsigned short us4;

__device__ __forceinline__ float hsig(float x) {
    return fminf(fmaxf(0.2f * x + 0.5f, 0.f), 1.f);
}
__device__ __forceinline__ unsigned short f2bf(float v) {
    __hip_bfloat16 h = __float2bfloat16(v);   // RNE
    unsigned short u; __builtin_memcpy(&u, &h, 2); return u;
}
__device__ __forceinline__ float bf2f(unsigned short u) {
    __hip_bfloat16 h; __builtin_memcpy(&h, &u, 2); return __bfloat162float(h);
}

// ============ fused ConvLSTM timestep via split-bf16 MFMA implicit GEMM ======
// z[p, co'] = sum_{s,dd,ci} src_s[p+dd, ci] * W_s[dd, ci, co'];  co' = c*4+g.
// Activations split a = a_hi + a_lo (two bf16); weights bf16 (hi only).
// 2 MFMAs per K-chunk: acc = Ah*Bh + Al*Bh = (Ah+Al)*Bh  -> weight-quant
// limited accuracy (~1e-4 rel), activations near-fp32.
// B operands are read DIRECTLY FROM GLOBAL (coalesced 1KB/wave, L1-broadcast
// across the 4 waves, L2-resident stream) -> no ldsB, no per-tap barriers.
// LDS holds only the A halo tile (hi+lo planes, pitch 40 ush = 2-way banks).
template<int TILE>
__global__ __launch_bounds__(256, (TILE == 16) ? 3 : 4)
void lstm_mfma(const float* __restrict__ xin, const float* __restrict__ hprev,
               float* __restrict__ cst, float* __restrict__ hout,
               const unsigned short* __restrict__ BtX,
               const unsigned short* __restrict__ BtH,
               const float* __restrict__ bias,
               int H, int W, int CiR, int CiP, int C)
{
    constexpr int HS = TILE + 2;
    constexpr int PITCH = 40;                    // ushorts per pixel (32+8 pad)
    constexpr int APLANE = HS * HS * PITCH;      // ushorts per plane
    constexpr int NSLOT = HS * HS * 8;           // float4 staging slots
    constexpr int NFM = (TILE == 16) ? 4 : 2;    // m-frags per wave
    constexpr int NN  = (TILE == 16) ? 4 : 2;    // n-grps per wave
    extern __shared__ char smem[];
    unsigned short* ldsA = (unsigned short*)smem;          // [2][APLANE]

    const int tid = threadIdx.x, w = tid >> 6, lane = tid & 63;
    const int nb = blockIdx.z;
    const int y0 = blockIdx.y * TILE, x0 = blockIdx.x * TILE;
    const int NG = (4 * C) >> 4;
    const int kq = lane >> 4;

    // per-lane A base offset (ushorts, within plane; row-part included)
    int abase;
    if (TILE == 16) abase = (w * 4) * HS * PITCH + (lane & 15) * PITCH + kq * 8;
    else abase = ((w >> 1) * 4 + ((lane >> 3) & 1)) * HS * PITCH + (lane & 7) * PITCH + kq * 8;

    f32x4 acc[NFM][NN];
#pragma unroll
    for (int a = 0; a < NFM; ++a)
#pragma unroll
        for (int b = 0; b < NN; ++b) acc[a][b] = (f32x4)0.f;

    for (int s = 0; s < 2; ++s) {
        if (s == 1 && hprev == nullptr) break;   // t==0: conv(0,U)==0
        const float* __restrict__ src = s ? hprev : xin;
        const int CsR = s ? C : CiR;
        const int CsP = s ? C : CiP;
        const unsigned short* __restrict__ Bt = s ? BtH : BtX;
        const int nch = CsP >> 5;

        for (int ck = 0; ck < nch; ++ck) {
            __syncthreads();                     // protect ldsA from prev chunk
            const int ci0 = ck << 5;
            // ---- stage A halo tile (fp32 -> bf16 hi/lo planes) ----
            for (int i = tid; i < NSLOT; i += 256) {
                const int pix = i >> 3, c4 = (i & 7) << 2;
                const int hy = pix / HS, hx = pix - hy * HS;
                const int iy = y0 + hy - 1, ix = x0 + hx - 1;
                float4 v = make_float4(0.f, 0.f, 0.f, 0.f);
                if (iy >= 0 && iy < H && ix >= 0 && ix < W) {
                    const float* gp = src + ((size_t)iy * W + ix) * CsR + ci0 + c4;
                    if (ci0 + c4 + 4 <= CsR) v = *(const float4*)gp;
                    else {
                        const int rem = CsR - ci0 - c4;
                        if (rem > 0) { v.x = gp[0]; if (rem > 1) v.y = gp[1]; if (rem > 2) v.z = gp[2]; }
                    }
                }
                const float f[4] = {v.x, v.y, v.z, v.w};
                us4 hi, lo;
#pragma unroll
                for (int e = 0; e < 4; ++e) {
                    const unsigned short h = f2bf(f[e]);
                    hi[e] = h; lo[e] = f2bf(f[e] - bf2f(h));
                }
                const int off = pix * PITCH + c4;
                *(us4*)(ldsA + off) = hi;
                *(us4*)(ldsA + APLANE + off) = lo;
            }
            __syncthreads();
            // ---- 9 taps; B frags straight from global (uniform base + lane*8) ----
#pragma unroll
            for (int dd = 0; dd < 9; ++dd) {
                const int dy = dd / 3, dx = dd % 3;
                short8v bh[NN];
#pragma unroll
                for (int nn = 0; nn < NN; ++nn) {
                    const int ng = (TILE == 16) ? nn : ((w & 1) * 2 + nn);
                    const size_t bbase =
                        ((size_t)((ck * 9 + dd) * NG + nb * 4 + ng) << 9) + lane * 8;
                    bh[nn] = *(const short8v*)(Bt + bbase);
                }
                short8v ah[NFM], al[NFM];
#pragma unroll
                for (int fm = 0; fm < NFM; ++fm) {
                    const int ro = (TILE == 16) ? (fm + dy) : (2 * fm + dy);
                    ah[fm] = *(const short8v*)(ldsA + abase + (ro * HS + dx) * PITCH);
                    al[fm] = *(const short8v*)(ldsA + APLANE + abase + (ro * HS + dx) * PITCH);
                }
#pragma unroll
                for (int nn = 0; nn < NN; ++nn)
#pragma unroll
                    for (int fm = 0; fm < NFM; ++fm) {
                        acc[fm][nn] = __builtin_amdgcn_mfma_f32_16x16x32_bf16(ah[fm], bh[nn], acc[fm][nn], 0, 0, 0);
                        acc[fm][nn] = __builtin_amdgcn_mfma_f32_16x16x32_bf16(al[fm], bh[nn], acc[fm][nn], 0, 0, 0);
                    }
            }
        }
    }

    // ---- epilogue: transpose D frags via LDS, apply gates ----
    __syncthreads();
    float* lds2 = (float*)smem + w * 276;    // 16x17 pad, per-wave scratch
    const int rr = lane & 15, cl = lane >> 4;
#pragma unroll
    for (int nn = 0; nn < NN; ++nn) {
        const int ngl = (TILE == 16) ? nn : ((w & 1) * 2 + nn);
        const int c = nb * 16 + ngl * 4 + cl;           // channel in [0,C)
        float b4[4];
#pragma unroll
        for (int g = 0; g < 4; ++g) b4[g] = bias[g * C + c];
#pragma unroll
        for (int fm = 0; fm < NFM; ++fm) {
            // D layout: lane holds col=lane&15, rows (lane>>4)*4+j
#pragma unroll
            for (int j = 0; j < 4; ++j) lds2[(cl * 4 + j) * 17 + rr] = acc[fm][nn][j];
            float z[4];
#pragma unroll
            for (int g = 0; g < 4; ++g) z[g] = lds2[rr * 17 + cl * 4 + g];
            int py, px;
            if (TILE == 16) { py = y0 + w * 4 + fm; px = x0 + rr; }
            else { py = y0 + (w >> 1) * 4 + 2 * fm + (rr >> 3); px = x0 + (rr & 7); }
            const size_t base = ((size_t)py * W + px) * C + c;
            const float cold = hprev ? cst[base] : 0.f;
            const float zi = z[0] + b4[0], zf = z[1] + b4[1];
            const float zc = z[2] + b4[2], zo = z[3] + b4[3];
            const float cn = hsig(zf) * cold + hsig(zi) * fmaxf(zc, 0.f);
            const float hv = hsig(zo) * fmaxf(cn, 0.f);
            cst[base] = cn; hout[base] = hv;
        }
    }
}

// ===== weight pre-transform: fp32 [3][3][Cs][4C] -> fragment-ordered bf16 =====
// layout: [ck][dd][ngrp][lane 0..63][8] (hi plane only), k = ck*32+(lane>>4)*8+e,
// co' = ngrp*16 + (lane&15) = c*4+g  ->  src co = g*C + c.  ci>=CsR zero-filled.
__global__ void transform_w_kernel(const float* __restrict__ Wsrc,
                                   unsigned short* __restrict__ Bt,
                                   int CsR, int C, int total)
{
    const int i = blockIdx.x * 256 + threadIdx.x;
    if (i >= total) return;
    const int N = 4 * C, NG = N >> 4;
    const int lane = i & 63; int t = i >> 6;
    const int ng = t % NG; t /= NG;
    const int dd = t % 9; const int ck = t / 9;
    const int colp = ng * 16 + (lane & 15);
    const int c = colp >> 2, g = colp & 3, co = g * C + c;
    const int kb = (lane >> 4) * 8;
    short8v hi8;
#pragma unroll
    for (int e = 0; e < 8; ++e) {
        const int ci = (ck << 5) + kb + e;
        const float v = (ci < CsR) ? Wsrc[(size_t)(dd * CsR + ci) * N + co] : 0.f;
        hi8[e] = (short)f2bf(v);
    }
    const size_t base = ((size_t)(ck * 9 + dd) * NG + ng) * 512 + lane * 8;
    *(short8v*)(Bt + base) = hi8;
}

// ---------------- MaxPool (1,2,2), NHWC, float4 over channels ----------------
__global__ void pool_kernel(const float* __restrict__ in, float* __restrict__ out,
                            int H, int Wd, int C, long total4)
{
    const int Ho = H >> 1, Wo = Wd >> 1;
    const int C4 = C >> 2;
    for (long i = (long)blockIdx.x * blockDim.x + threadIdx.x; i < total4;
         i += (long)gridDim.x * blockDim.x) {
        const int c4 = (int)(i % C4);
        long r = i / C4;
        const int x = (int)(r % Wo); r /= Wo;
        const int y = (int)(r % Ho);
        const int t = (int)(r / Ho);
        const float4* a = reinterpret_cast<const float4*>(in) +
                          (((long)t * H + 2 * y) * Wd + 2 * x) * C4 + c4;
        const float4 v00 = a[0], v01 = a[C4];
        const float4 v10 = a[(long)Wd * C4], v11 = a[(long)Wd * C4 + C4];
        float4 o;
        o.x = fmaxf(fmaxf(v00.x, v01.x), fmaxf(v10.x, v11.x));
        o.y = fmaxf(fmaxf(v00.y, v01.y), fmaxf(v10.y, v11.y));
        o.z = fmaxf(fmaxf(v00.z, v01.z), fmaxf(v10.z, v11.z));
        o.w = fmaxf(fmaxf(v00.w, v01.w), fmaxf(v10.w, v11.w));
        reinterpret_cast<float4*>(out)[i] = o;
    }
}

// ------------- concat([A, up2x2(B)], channel-last), float4 -------------
__global__ void upconcat_kernel(const float* __restrict__ A, const float* __restrict__ B,
                                float* __restrict__ out, int H, int Wd, int C1, int C2,
                                long total4)
{
    const int Co4 = (C1 + C2) >> 2, C14 = C1 >> 2, C24 = C2 >> 2;
    for (long i = (long)blockIdx.x * blockDim.x + threadIdx.x; i < total4;
         i += (long)gridDim.x * blockDim.x) {
        const int c4 = (int)(i % Co4);
        long r = i / Co4;
        const int x = (int)(r % Wd); r /= Wd;
        const int y = (int)(r % H);
        const int t = (int)(r / H);
        float4 v;
        if (c4 < C14)
            v = reinterpret_cast<const float4*>(A)[(((long)t * H + y) * Wd + x) * C14 + c4];
        else
            v = reinterpret_cast<const float4*>(B)[
                (((long)t * (H >> 1) + (y >> 1)) * (Wd >> 1) + (x >> 1)) * C24 + (c4 - C14)];
        reinterpret_cast<float4*>(out)[i] = v;
    }
}

// ------------- final 1x1 ConvLSTM, Cin=32 -> C=1 -------------
__global__ void final_step_kernel(const float* __restrict__ h7, const float* __restrict__ hprev,
                                  float* __restrict__ cst, float* __restrict__ hout,
                                  const float* __restrict__ wout,  // [32][4]
                                  const float* __restrict__ uout,  // [4]
                                  const float* __restrict__ bout,  // [4]
                                  float* __restrict__ dout, int N)
{
    const int i = blockIdx.x * 256 + threadIdx.x;
    if (i >= N) return;
    float z0 = bout[0], z1 = bout[1], z2 = bout[2], z3 = bout[3];
    const float* hp = h7 + (size_t)i * 32;
#pragma unroll
    for (int c = 0; c < 32; c += 4) {
        const float4 h4 = *reinterpret_cast<const float4*>(hp + c);
        const float hv4[4] = {h4.x, h4.y, h4.z, h4.w};
#pragma unroll
        for (int j = 0; j < 4; ++j) {
            z0 += hv4[j] * wout[(c + j) * 4 + 0];
            z1 += hv4[j] * wout[(c + j) * 4 + 1];
            z2 += hv4[j] * wout[(c + j) * 4 + 2];
            z3 += hv4[j] * wout[(c + j) * 4 + 3];
        }
    }
    float hpv = 0.f, cold = 0.f;
    if (hprev) { hpv = hprev[i]; cold = cst[i]; }
    z0 += hpv * uout[0]; z1 += hpv * uout[1]; z2 += hpv * uout[2]; z3 += hpv * uout[3];
    const float ig = hsig(z0), fg = hsig(z1), og = hsig(z3);
    const float cd = fmaxf(z2, 0.f);
    const float cn = fg * cold + ig * cd;
    const float hv = og * fmaxf(cn, 0.f);
    cst[i] = cn; hout[i] = hv;
    if (dout) dout[i] = hv;
}

// ---------------- host orchestration ----------------
struct LD { int H, W, CiR, CiP, C, tile, wi; };

static void run_layer(const LD& L, const float* in, float* out, float* cstate,
                      const unsigned short* btx, const unsigned short* bth,
                      const float* bias, hipStream_t stream)
{
    const size_t inS = (size_t)L.H * L.W * L.CiR, outS = (size_t)L.H * L.W * L.C;
    const dim3 grid(L.W / L.tile, L.H / L.tile, (4 * L.C) / 64);
    for (int t = 0; t < T_STEPS; ++t) {
        const float* hp = t ? out + (t - 1) * outS : nullptr;
        if (L.tile == 16) {
            const size_t sh = (size_t)18 * 18 * 40 * 2 * 2;   // 51840 B
            lstm_mfma<16><<<grid, 256, sh, stream>>>(in + t * inS, hp, cstate, out + t * outS,
                                                     btx, bth, bias, L.H, L.W, L.CiR, L.CiP, L.C);
        } else {
            const size_t sh = (size_t)10 * 10 * 40 * 2 * 2;   // 16000 B
            lstm_mfma<8><<<grid, 256, sh, stream>>>(in + t * inS, hp, cstate, out + t * outS,
                                                    btx, bth, bias, L.H, L.W, L.CiR, L.CiP, L.C);
        }
    }
}

extern "C" void kernel_launch(void* const* d_in, const int* in_sizes, int n_in,
                              void* d_out, int out_size, void* d_ws, size_t ws_size,
                              hipStream_t stream)
{
    (void)in_sizes; (void)n_in; (void)out_size; (void)ws_size;
    const float* x = (const float*)d_in[0];
    auto Wp = [&](int k) { return (const float*)d_in[k]; };
    char* ws = (char*)d_ws;
    const size_t MiB = 1ull << 20;
    auto f = [&](size_t m) { return (float*)(ws + m * MiB); };

    hipFuncSetAttribute((const void*)lstm_mfma<16>,
                        hipFuncAttributeMaxDynamicSharedMemorySize, 52224);
    hipFuncSetAttribute((const void*)lstm_mfma<8>,
                        hipFuncAttributeMaxDynamicSharedMemorySize, 16384);

    // Arena (peak ~210 MiB; lifetimes hand-checked):
    float* bC1  = f(0);    float* bC2  = f(32);  float* bC3  = f(48);
    float* bCST = f(56);   // shared c-state, <= 8 MiB
    float* bHF  = (float*)(ws + 64 * MiB);
    float* bCF  = (float*)(ws + 64 * MiB + 256 * 1024);
    float* bS1A = f(65);   float* bP1  = f(97);  float* bS2A = f(105);
    float* bP2  = f(97);   float* bS3A = f(101); float* bP3  = f(65);
    float* bS4A = f(67);   float* bC4  = f(71);  float* bM5  = f(75);
    float* bS5A = f(99);   float* bC5  = f(65);  float* bM6  = f(73);
    float* bS6A = f(121);  float* bC6  = f(65);  float* bM7  = f(81);
    float* bS7A = f(0);    float* bC7  = f(81);

    static const LD Ls[14] = {
        {256, 256,   1,  32,  32, 16,  1}, {256, 256,  32,  32,  32, 16,  4},
        {128, 128,  32,  32,  64, 16,  7}, {128, 128,  64,  64,  64, 16, 10},
        { 64,  64,  64,  64, 128,  8, 13}, { 64,  64, 128, 128, 128,  8, 16},
        { 32,  32, 128, 128, 256,  8, 19}, { 32,  32, 256, 256, 256,  8, 22},
        { 64,  64, 384, 384, 128,  8, 25}, { 64,  64, 128, 128, 128,  8, 28},
        {128, 128, 192, 192,  64, 16, 31}, {128, 128,  64,  64,  64, 16, 34},
        {256, 256,  96,  96,  32, 16, 37}, {256, 256,  32,  32,  32, 16, 40},
    };

    // ---- weight transforms into Bt arena at [177 MiB, ...) ----
    unsigned short* btx[14]; unsigned short* bth[14];
    {
        size_t cur = 177 * MiB;
        for (int i = 0; i < 14; ++i) {
            const LD& L = Ls[i];
            const int NG = (4 * L.C) >> 4;
            const size_t szx = (size_t)(L.CiP >> 5) * 9 * NG * 1024;  // bytes
            const size_t szh = (size_t)(L.C  >> 5) * 9 * NG * 1024;
            btx[i] = (unsigned short*)(ws + cur); cur += szx;
            bth[i] = (unsigned short*)(ws + cur); cur += szh;
            const int totx = (L.CiP >> 5) * 9 * NG * 64;
            const int toth = (L.C  >> 5) * 9 * NG * 64;
            transform_w_kernel<<<(totx + 255) / 256, 256, 0, stream>>>(
                Wp(L.wi), btx[i], L.CiR, L.C, totx);
            transform_w_kernel<<<(toth + 255) / 256, 256, 0, stream>>>(
                Wp(L.wi + 1), bth[i], L.C, L.C, toth);
        }
    }

    auto pool = [&](const float* in, float* out, int H, int Wd, int C) {
        long total4 = (long)T_STEPS * (H / 2) * (Wd / 2) * (C / 4);
        long nb = (total4 + 255) / 256; if (nb > 4096) nb = 4096;
        pool_kernel<<<dim3((unsigned)nb), 256, 0, stream>>>(in, out, H, Wd, C, total4);
    };
    auto upcat = [&](const float* A, const float* B, float* out, int H, int Wd, int C1, int C2) {
        long total4 = (long)T_STEPS * H * Wd * ((C1 + C2) / 4);
        long nb = (total4 + 255) / 256; if (nb > 8192) nb = 8192;
        upconcat_kernel<<<dim3((unsigned)nb), 256, 0, stream>>>(A, B, out, H, Wd, C1, C2, total4);
    };
    auto run = [&](int i, const float* in, float* out) {
        run_layer(Ls[i], in, out, bCST, btx[i], bth[i], Wp(Ls[i].wi + 2), stream);
    };

    run(0, x, bS1A);        run(1, bS1A, bC1);
    pool(bC1, bP1, 256, 256, 32);
    run(2, bP1, bS2A);      run(3, bS2A, bC2);
    pool(bC2, bP2, 128, 128, 64);
    run(4, bP2, bS3A);      run(5, bS3A, bC3);
    pool(bC3, bP3, 64, 64, 128);
    run(6, bP3, bS4A);      run(7, bS4A, bC4);
    upcat(bC3, bC4, bM5, 64, 64, 128, 256);
    run(8, bM5, bS5A);      run(9, bS5A, bC5);
    upcat(bC2, bC5, bM6, 128, 128, 64, 128);
    run(10, bM6, bS6A);     run(11, bS6A, bC6);
    upcat(bC1, bC6, bM7, 256, 256, 32, 64);
    run(12, bM7, bS7A);     run(13, bS7A, bC7);

    const int N = 256 * 256;
    for (int t = 0; t < T_STEPS; ++t) {
        const float* h7 = bC7 + (size_t)t * N * 32;
        final_step_kernel<<<N / 256, 256, 0, stream>>>(
            h7, t ? bHF : nullptr, bCF, bHF, Wp(43), Wp(44), Wp(45),
            (t == T_STEPS - 1) ? (float*)d_out : nullptr, N);
    }
}

// Round 4
// 2145.694 us; speedup vs baseline: 5.5298x; 1.3641x over previous
//
#include <hip/hip_runtime.h>
#include <hip/hip_bf16.h>

#define T_STEPS 4

typedef __attribute__((ext_vector_type(8))) short short8v;   // 8 x bf16 bits
typedef __attribute__((ext_vector_type(4))) float f32x4;
typedef __attribute__((ext_vector_type(4))) unsigned short us4;

__device__ __forceinline__ float hsig(float x) {
    return fminf(fmaxf(0.2f * x + 0.5f, 0.f), 1.f);
}
__device__ __forceinline__ unsigned short f2bf(float v) {
    __hip_bfloat16 h = __float2bfloat16(v);   // RNE
    unsigned short u; __builtin_memcpy(&u, &h, 2); return u;
}

// ============ fused ConvLSTM timestep via bf16 MFMA implicit GEMM ============
// z[p, co'] = sum_{s,dd,ci} src_s[p+dd, ci] * W_s[dd, ci, co'];  co' = c*4+g.
// Pure bf16 operands (net saturates -> error headroom measured in R2/R3).
// B fragments read DIRECTLY FROM GLOBAL with a 1-tap register double-buffer:
// tap0 primed before the staging barrier; tap d+1 prefetched during tap d's
// MFMAs -> global latency hidden, no ldsB, no per-tap barriers.
// LDS holds only the bf16 A halo tile (pitch 40 ush = 2-way banks, free).
template<int TILE>
__global__ __launch_bounds__(256, (TILE == 16) ? 3 : 6)
void lstm_mfma(const float* __restrict__ xin, const float* __restrict__ hprev,
               float* __restrict__ cst, float* __restrict__ hout,
               const unsigned short* __restrict__ BtX,
               const unsigned short* __restrict__ BtH,
               const float* __restrict__ bias,
               int H, int W, int CiR, int CiP, int C)
{
    constexpr int HS = TILE + 2;
    constexpr int PITCH = 40;                    // ushorts per pixel (32+8 pad)
    constexpr int NSLOT = HS * HS * 8;           // float4 staging slots
    constexpr int NFM = (TILE == 16) ? 4 : 2;    // m-frags per wave
    constexpr int NN  = (TILE == 16) ? 4 : 2;    // n-grps per wave
    extern __shared__ char smem[];
    unsigned short* ldsA = (unsigned short*)smem;

    const int tid = threadIdx.x, w = tid >> 6, lane = tid & 63;
    const int nb = blockIdx.z;
    const int y0 = blockIdx.y * TILE, x0 = blockIdx.x * TILE;
    const int NG = (4 * C) >> 4;
    const int kq = lane >> 4;

    // per-lane A base offset (ushorts; row-part included)
    int abase;
    if (TILE == 16) abase = (w * 4) * HS * PITCH + (lane & 15) * PITCH + kq * 8;
    else abase = ((w >> 1) * 4 + ((lane >> 3) & 1)) * HS * PITCH + (lane & 7) * PITCH + kq * 8;

    f32x4 acc[NFM][NN];
#pragma unroll
    for (int a = 0; a < NFM; ++a)
#pragma unroll
        for (int b = 0; b < NN; ++b) acc[a][b] = (f32x4)0.f;

    for (int s = 0; s < 2; ++s) {
        if (s == 1 && hprev == nullptr) break;   // t==0: conv(0,U)==0
        const float* __restrict__ src = s ? hprev : xin;
        const int CsR = s ? C : CiR;
        const int CsP = s ? C : CiP;
        const unsigned short* __restrict__ Bt = s ? BtH : BtX;
        const int nch = CsP >> 5;

        for (int ck = 0; ck < nch; ++ck) {
            __syncthreads();                     // protect ldsA from prev chunk
            const int ci0 = ck << 5;
            // ---- stage A halo tile (fp32 -> bf16) ----
            for (int i = tid; i < NSLOT; i += 256) {
                const int pix = i >> 3, c4 = (i & 7) << 2;
                const int hy = pix / HS, hx = pix - hy * HS;
                const int iy = y0 + hy - 1, ix = x0 + hx - 1;
                float4 v = make_float4(0.f, 0.f, 0.f, 0.f);
                if (iy >= 0 && iy < H && ix >= 0 && ix < W) {
                    const float* gp = src + ((size_t)iy * W + ix) * CsR + ci0 + c4;
                    if (ci0 + c4 + 4 <= CsR) v = *(const float4*)gp;
                    else {
                        const int rem = CsR - ci0 - c4;
                        if (rem > 0) { v.x = gp[0]; if (rem > 1) v.y = gp[1]; if (rem > 2) v.z = gp[2]; }
                    }
                }
                us4 hi;
                hi[0] = f2bf(v.x); hi[1] = f2bf(v.y);
                hi[2] = f2bf(v.z); hi[3] = f2bf(v.w);
                *(us4*)(ldsA + pix * PITCH + c4) = hi;
            }
            // ---- prime tap-0 B frags (independent of LDS -> overlaps barrier) ----
            short8v bcur[NN], bnxt[NN];
#pragma unroll
            for (int nn = 0; nn < NN; ++nn) {
                const int ng = (TILE == 16) ? nn : ((w & 1) * 2 + nn);
                bcur[nn] = *(const short8v*)(Bt +
                    ((size_t)((ck * 9) * NG + nb * 4 + ng) << 9) + lane * 8);
            }
            __syncthreads();
            // ---- 9 taps, register-pipelined B ----
#pragma unroll
            for (int dd = 0; dd < 9; ++dd) {
                if (dd < 8) {
#pragma unroll
                    for (int nn = 0; nn < NN; ++nn) {
                        const int ng = (TILE == 16) ? nn : ((w & 1) * 2 + nn);
                        bnxt[nn] = *(const short8v*)(Bt +
                            ((size_t)((ck * 9 + dd + 1) * NG + nb * 4 + ng) << 9) + lane * 8);
                    }
                }
                const int dy = dd / 3, dx = dd % 3;
                short8v ah[NFM];
#pragma unroll
                for (int fm = 0; fm < NFM; ++fm) {
                    const int ro = (TILE == 16) ? (fm + dy) : (2 * fm + dy);
                    ah[fm] = *(const short8v*)(ldsA + abase + (ro * HS + dx) * PITCH);
                }
#pragma unroll
                for (int nn = 0; nn < NN; ++nn)
#pragma unroll
                    for (int fm = 0; fm < NFM; ++fm)
                        acc[fm][nn] = __builtin_amdgcn_mfma_f32_16x16x32_bf16(ah[fm], bcur[nn], acc[fm][nn], 0, 0, 0);
                if (dd < 8) {
#pragma unroll
                    for (int nn = 0; nn < NN; ++nn) bcur[nn] = bnxt[nn];
                }
            }
        }
    }

    // ---- epilogue: transpose D frags via LDS, apply gates ----
    __syncthreads();
    float* lds2 = (float*)smem + w * 276;    // 16x17 pad, per-wave scratch
    const int rr = lane & 15, cl = lane >> 4;
#pragma unroll
    for (int nn = 0; nn < NN; ++nn) {
        const int ngl = (TILE == 16) ? nn : ((w & 1) * 2 + nn);
        const int c = nb * 16 + ngl * 4 + cl;           // channel in [0,C)
        float b4[4];
#pragma unroll
        for (int g = 0; g < 4; ++g) b4[g] = bias[g * C + c];
#pragma unroll
        for (int fm = 0; fm < NFM; ++fm) {
            // D layout: lane holds col=lane&15, rows (lane>>4)*4+j
#pragma unroll
            for (int j = 0; j < 4; ++j) lds2[(cl * 4 + j) * 17 + rr] = acc[fm][nn][j];
            float z[4];
#pragma unroll
            for (int g = 0; g < 4; ++g) z[g] = lds2[rr * 17 + cl * 4 + g];
            int py, px;
            if (TILE == 16) { py = y0 + w * 4 + fm; px = x0 + rr; }
            else { py = y0 + (w >> 1) * 4 + 2 * fm + (rr >> 3); px = x0 + (rr & 7); }
            const size_t base = ((size_t)py * W + px) * C + c;
            const float cold = hprev ? cst[base] : 0.f;
            const float zi = z[0] + b4[0], zf = z[1] + b4[1];
            const float zc = z[2] + b4[2], zo = z[3] + b4[3];
            const float cn = hsig(zf) * cold + hsig(zi) * fmaxf(zc, 0.f);
            const float hv = hsig(zo) * fmaxf(cn, 0.f);
            cst[base] = cn; hout[base] = hv;
        }
    }
}

// ===== weight pre-transform: fp32 [3][3][Cs][4C] -> fragment-ordered bf16 =====
// layout: [ck][dd][ngrp][lane 0..63][8], k = ck*32+(lane>>4)*8+e,
// co' = ngrp*16 + (lane&15) = c*4+g  ->  src co = g*C + c.  ci>=CsR zero-filled.
__global__ void transform_w_kernel(const float* __restrict__ Wsrc,
                                   unsigned short* __restrict__ Bt,
                                   int CsR, int C, int total)
{
    const int i = blockIdx.x * 256 + threadIdx.x;
    if (i >= total) return;
    const int N = 4 * C, NG = N >> 4;
    const int lane = i & 63; int t = i >> 6;
    const int ng = t % NG; t /= NG;
    const int dd = t % 9; const int ck = t / 9;
    const int colp = ng * 16 + (lane & 15);
    const int c = colp >> 2, g = colp & 3, co = g * C + c;
    const int kb = (lane >> 4) * 8;
    short8v hi8;
#pragma unroll
    for (int e = 0; e < 8; ++e) {
        const int ci = (ck << 5) + kb + e;
        const float v = (ci < CsR) ? Wsrc[(size_t)(dd * CsR + ci) * N + co] : 0.f;
        hi8[e] = (short)f2bf(v);
    }
    const size_t base = ((size_t)(ck * 9 + dd) * NG + ng) * 512 + lane * 8;
    *(short8v*)(Bt + base) = hi8;
}

// ---------------- MaxPool (1,2,2), NHWC, float4 over channels ----------------
__global__ void pool_kernel(const float* __restrict__ in, float* __restrict__ out,
                            int H, int Wd, int C, long total4)
{
    const int Ho = H >> 1, Wo = Wd >> 1;
    const int C4 = C >> 2;
    for (long i = (long)blockIdx.x * blockDim.x + threadIdx.x; i < total4;
         i += (long)gridDim.x * blockDim.x) {
        const int c4 = (int)(i % C4);
        long r = i / C4;
        const int x = (int)(r % Wo); r /= Wo;
        const int y = (int)(r % Ho);
        const int t = (int)(r / Ho);
        const float4* a = reinterpret_cast<const float4*>(in) +
                          (((long)t * H + 2 * y) * Wd + 2 * x) * C4 + c4;
        const float4 v00 = a[0], v01 = a[C4];
        const float4 v10 = a[(long)Wd * C4], v11 = a[(long)Wd * C4 + C4];
        float4 o;
        o.x = fmaxf(fmaxf(v00.x, v01.x), fmaxf(v10.x, v11.x));
        o.y = fmaxf(fmaxf(v00.y, v01.y), fmaxf(v10.y, v11.y));
        o.z = fmaxf(fmaxf(v00.z, v01.z), fmaxf(v10.z, v11.z));
        o.w = fmaxf(fmaxf(v00.w, v01.w), fmaxf(v10.w, v11.w));
        reinterpret_cast<float4*>(out)[i] = o;
    }
}

// ------------- concat([A, up2x2(B)], channel-last), float4 -------------
__global__ void upconcat_kernel(const float* __restrict__ A, const float* __restrict__ B,
                                float* __restrict__ out, int H, int Wd, int C1, int C2,
                                long total4)
{
    const int Co4 = (C1 + C2) >> 2, C14 = C1 >> 2, C24 = C2 >> 2;
    for (long i = (long)blockIdx.x * blockDim.x + threadIdx.x; i < total4;
         i += (long)gridDim.x * blockDim.x) {
        const int c4 = (int)(i % Co4);
        long r = i / Co4;
        const int x = (int)(r % Wd); r /= Wd;
        const int y = (int)(r % H);
        const int t = (int)(r / H);
        float4 v;
        if (c4 < C14)
            v = reinterpret_cast<const float4*>(A)[(((long)t * H + y) * Wd + x) * C14 + c4];
        else
            v = reinterpret_cast<const float4*>(B)[
                (((long)t * (H >> 1) + (y >> 1)) * (Wd >> 1) + (x >> 1)) * C24 + (c4 - C14)];
        reinterpret_cast<float4*>(out)[i] = v;
    }
}

// ------------- final 1x1 ConvLSTM, Cin=32 -> C=1 -------------
__global__ void final_step_kernel(const float* __restrict__ h7, const float* __restrict__ hprev,
                                  float* __restrict__ cst, float* __restrict__ hout,
                                  const float* __restrict__ wout,  // [32][4]
                                  const float* __restrict__ uout,  // [4]
                                  const float* __restrict__ bout,  // [4]
                                  float* __restrict__ dout, int N)
{
    const int i = blockIdx.x * 256 + threadIdx.x;
    if (i >= N) return;
    float z0 = bout[0], z1 = bout[1], z2 = bout[2], z3 = bout[3];
    const float* hp = h7 + (size_t)i * 32;
#pragma unroll
    for (int c = 0; c < 32; c += 4) {
        const float4 h4 = *reinterpret_cast<const float4*>(hp + c);
        const float hv4[4] = {h4.x, h4.y, h4.z, h4.w};
#pragma unroll
        for (int j = 0; j < 4; ++j) {
            z0 += hv4[j] * wout[(c + j) * 4 + 0];
            z1 += hv4[j] * wout[(c + j) * 4 + 1];
            z2 += hv4[j] * wout[(c + j) * 4 + 2];
            z3 += hv4[j] * wout[(c + j) * 4 + 3];
        }
    }
    float hpv = 0.f, cold = 0.f;
    if (hprev) { hpv = hprev[i]; cold = cst[i]; }
    z0 += hpv * uout[0]; z1 += hpv * uout[1]; z2 += hpv * uout[2]; z3 += hpv * uout[3];
    const float ig = hsig(z0), fg = hsig(z1), og = hsig(z3);
    const float cd = fmaxf(z2, 0.f);
    const float cn = fg * cold + ig * cd;
    const float hv = og * fmaxf(cn, 0.f);
    cst[i] = cn; hout[i] = hv;
    if (dout) dout[i] = hv;
}

// ---------------- host orchestration ----------------
struct LD { int H, W, CiR, CiP, C, tile, wi; };

static void run_layer(const LD& L, const float* in, float* out, float* cstate,
                      const unsigned short* btx, const unsigned short* bth,
                      const float* bias, hipStream_t stream)
{
    const size_t inS = (size_t)L.H * L.W * L.CiR, outS = (size_t)L.H * L.W * L.C;
    const dim3 grid(L.W / L.tile, L.H / L.tile, (4 * L.C) / 64);
    for (int t = 0; t < T_STEPS; ++t) {
        const float* hp = t ? out + (t - 1) * outS : nullptr;
        if (L.tile == 16) {
            const size_t sh = (size_t)18 * 18 * 40 * 2;   // 25920 B
            lstm_mfma<16><<<grid, 256, sh, stream>>>(in + t * inS, hp, cstate, out + t * outS,
                                                     btx, bth, bias, L.H, L.W, L.CiR, L.CiP, L.C);
        } else {
            const size_t sh = (size_t)10 * 10 * 40 * 2;   // 8000 B
            lstm_mfma<8><<<grid, 256, sh, stream>>>(in + t * inS, hp, cstate, out + t * outS,
                                                    btx, bth, bias, L.H, L.W, L.CiR, L.CiP, L.C);
        }
    }
}

extern "C" void kernel_launch(void* const* d_in, const int* in_sizes, int n_in,
                              void* d_out, int out_size, void* d_ws, size_t ws_size,
                              hipStream_t stream)
{
    (void)in_sizes; (void)n_in; (void)out_size; (void)ws_size;
    const float* x = (const float*)d_in[0];
    auto Wp = [&](int k) { return (const float*)d_in[k]; };
    char* ws = (char*)d_ws;
    const size_t MiB = 1ull << 20;
    auto f = [&](size_t m) { return (float*)(ws + m * MiB); };

    hipFuncSetAttribute((const void*)lstm_mfma<16>,
                        hipFuncAttributeMaxDynamicSharedMemorySize, 26624);
    hipFuncSetAttribute((const void*)lstm_mfma<8>,
                        hipFuncAttributeMaxDynamicSharedMemorySize, 8192);

    // Arena (peak ~210 MiB; lifetimes hand-checked):
    float* bC1  = f(0);    float* bC2  = f(32);  float* bC3  = f(48);
    float* bCST = f(56);   // shared c-state, <= 8 MiB
    float* bHF  = (float*)(ws + 64 * MiB);
    float* bCF  = (float*)(ws + 64 * MiB + 256 * 1024);
    float* bS1A = f(65);   float* bP1  = f(97);  float* bS2A = f(105);
    float* bP2  = f(97);   float* bS3A = f(101); float* bP3  = f(65);
    float* bS4A = f(67);   float* bC4  = f(71);  float* bM5  = f(75);
    float* bS5A = f(99);   float* bC5  = f(65);  float* bM6  = f(73);
    float* bS6A = f(121);  float* bC6  = f(65);  float* bM7  = f(81);
    float* bS7A = f(0);    float* bC7  = f(81);

    static const LD Ls[14] = {
        {256, 256,   1,  32,  32, 16,  1}, {256, 256,  32,  32,  32, 16,  4},
        {128, 128,  32,  32,  64,  8,  7}, {128, 128,  64,  64,  64,  8, 10},
        { 64,  64,  64,  64, 128,  8, 13}, { 64,  64, 128, 128, 128,  8, 16},
        { 32,  32, 128, 128, 256,  8, 19}, { 32,  32, 256, 256, 256,  8, 22},
        { 64,  64, 384, 384, 128,  8, 25}, { 64,  64, 128, 128, 128,  8, 28},
        {128, 128, 192, 192,  64,  8, 31}, {128, 128,  64,  64,  64,  8, 34},
        {256, 256,  96,  96,  32, 16, 37}, {256, 256,  32,  32,  32, 16, 40},
    };

    // ---- weight transforms into Bt arena at [177 MiB, ...) ----
    unsigned short* btx[14]; unsigned short* bth[14];
    {
        size_t cur = 177 * MiB;
        for (int i = 0; i < 14; ++i) {
            const LD& L = Ls[i];
            const int NG = (4 * L.C) >> 4;
            const size_t szx = (size_t)(L.CiP >> 5) * 9 * NG * 1024;  // bytes
            const size_t szh = (size_t)(L.C  >> 5) * 9 * NG * 1024;
            btx[i] = (unsigned short*)(ws + cur); cur += szx;
            bth[i] = (unsigned short*)(ws + cur); cur += szh;
            const int totx = (L.CiP >> 5) * 9 * NG * 64;
            const int toth = (L.C  >> 5) * 9 * NG * 64;
            transform_w_kernel<<<(totx + 255) / 256, 256, 0, stream>>>(
                Wp(L.wi), btx[i], L.CiR, L.C, totx);
            transform_w_kernel<<<(toth + 255) / 256, 256, 0, stream>>>(
                Wp(L.wi + 1), bth[i], L.C, L.C, toth);
        }
    }

    auto pool = [&](const float* in, float* out, int H, int Wd, int C) {
        long total4 = (long)T_STEPS * (H / 2) * (Wd / 2) * (C / 4);
        long nb = (total4 + 255) / 256; if (nb > 4096) nb = 4096;
        pool_kernel<<<dim3((unsigned)nb), 256, 0, stream>>>(in, out, H, Wd, C, total4);
    };
    auto upcat = [&](const float* A, const float* B, float* out, int H, int Wd, int C1, int C2) {
        long total4 = (long)T_STEPS * H * Wd * ((C1 + C2) / 4);
        long nb = (total4 + 255) / 256; if (nb > 8192) nb = 8192;
        upconcat_kernel<<<dim3((unsigned)nb), 256, 0, stream>>>(A, B, out, H, Wd, C1, C2, total4);
    };
    auto run = [&](int i, const float* in, float* out) {
        run_layer(Ls[i], in, out, bCST, btx[i], bth[i], Wp(Ls[i].wi + 2), stream);
    };

    run(0, x, bS1A);        run(1, bS1A, bC1);
    pool(bC1, bP1, 256, 256, 32);
    run(2, bP1, bS2A);      run(3, bS2A, bC2);
    pool(bC2, bP2, 128, 128, 64);
    run(4, bP2, bS3A);      run(5, bS3A, bC3);
    pool(bC3, bP3, 64, 64, 128);
    run(6, bP3, bS4A);      run(7, bS4A, bC4);
    upcat(bC3, bC4, bM5, 64, 64, 128, 256);
    run(8, bM5, bS5A);      run(9, bS5A, bC5);
    upcat(bC2, bC5, bM6, 128, 128, 64, 128);
    run(10, bM6, bS6A);     run(11, bS6A, bC6);
    upcat(bC1, bC6, bM7, 256, 256, 32, 64);
    run(12, bM7, bS7A);     run(13, bS7A, bC7);

    const int N = 256 * 256;
    for (int t = 0; t < T_STEPS; ++t) {
        const float* h7 = bC7 + (size_t)t * N * 32;
        final_step_kernel<<<N / 256, 256, 0, stream>>>(
            h7, t ? bHF : nullptr, bCF, bHF, Wp(43), Wp(44), Wp(45),
            (t == T_STEPS - 1) ? (float*)d_out : nullptr, N);
    }
}

// Round 5
// 1830.247 us; speedup vs baseline: 6.4829x; 1.1724x over previous
//
#include <hip/hip_runtime.h>
#include <hip/hip_bf16.h>

#define T_STEPS 4

typedef __attribute__((ext_vector_type(8))) short short8v;   // 8 x bf16 bits
typedef __attribute__((ext_vector_type(4))) float f32x4;
typedef __attribute__((ext_vector_type(4))) unsigned short us4;

__device__ __forceinline__ float hsig(float x) {
    return fminf(fmaxf(0.2f * x + 0.5f, 0.f), 1.f);
}
__device__ __forceinline__ unsigned short f2bf(float v) {
    __hip_bfloat16 h = __float2bfloat16(v);   // RNE
    unsigned short u; __builtin_memcpy(&u, &h, 2); return u;
}

// ============ fused ConvLSTM timestep via bf16 MFMA implicit GEMM ============
// z[p, co'] = sum_{s,dd,ci} src_s[p+dd, ci] * W_s[dd, ci, co'];  co' = c*4+g.
// Latency fix (R4): A-staging is split into ISSUE (11 unrolled independent
// global float4 loads into regs, issued for chunk t+1 right after the commit
// barrier so they fly under chunk t's 9-tap MFMA phase) and COMMIT (cvt+LDS
// write after the next barrier, whose vmcnt drain is then free). One exposed
// global latency per chunk instead of ~10 serialized ones.
// B fragments straight from global with per-tap register double-buffer.
template<int TILE>
__global__ __launch_bounds__(256, (TILE == 16) ? 2 : 4)
void lstm_mfma(const float* __restrict__ xin, const float* __restrict__ hprev,
               float* __restrict__ cst, float* __restrict__ hout,
               const unsigned short* __restrict__ BtX,
               const unsigned short* __restrict__ BtH,
               const float* __restrict__ bias,
               int H, int W, int CiR, int CiP, int C)
{
    constexpr int HS = TILE + 2;
    constexpr int PITCH = 40;                    // ushorts per pixel (32+8 pad)
    constexpr int NSLOT = HS * HS * 8;           // float4 staging slots
    constexpr int ITERS = (NSLOT + 255) / 256;   // 11 (TILE16) / 4 (TILE8)
    constexpr int NFM = (TILE == 16) ? 4 : 2;    // m-frags per wave
    constexpr int NN  = (TILE == 16) ? 4 : 2;    // n-grps per wave
    extern __shared__ char smem[];
    unsigned short* ldsA = (unsigned short*)smem;

    const int tid = threadIdx.x, w = tid >> 6, lane = tid & 63;
    const int nb = blockIdx.z;
    const int y0 = blockIdx.y * TILE, x0 = blockIdx.x * TILE;
    const int NG = (4 * C) >> 4;
    const int kq = lane >> 4;

    // per-lane A base offset (ushorts; row-part included)
    int abase;
    if (TILE == 16) abase = (w * 4) * HS * PITCH + (lane & 15) * PITCH + kq * 8;
    else abase = ((w >> 1) * 4 + ((lane >> 3) & 1)) * HS * PITCH + (lane & 7) * PITCH + kq * 8;

    f32x4 acc[NFM][NN];
#pragma unroll
    for (int a = 0; a < NFM; ++a)
#pragma unroll
        for (int b = 0; b < NN; ++b) acc[a][b] = (f32x4)0.f;

    const int nchx = CiP >> 5;
    const int nchh = hprev ? (C >> 5) : 0;       // t==0: conv(0,U)==0
    const int NCH = nchx + nchh;

    float4 stg[ITERS];
    // ---- ISSUE: batch all global loads for chunk t into stg regs ----
    auto issue = [&](int t) {
        const float* __restrict__ src = (t < nchx) ? xin : hprev;
        const int CsR = (t < nchx) ? CiR : C;
        const int ci0 = ((t < nchx) ? t : t - nchx) << 5;
#pragma unroll
        for (int it = 0; it < ITERS; ++it) {
            const int i = tid + it * 256;
            float4 v = make_float4(0.f, 0.f, 0.f, 0.f);
            if (i < NSLOT) {
                const int pix = i >> 3, c4 = (i & 7) << 2;
                const int hy = pix / HS, hx = pix - hy * HS;
                const int iy = y0 + hy - 1, ix = x0 + hx - 1;
                if (iy >= 0 && iy < H && ix >= 0 && ix < W) {
                    const float* gp = src + ((size_t)iy * W + ix) * CsR + ci0 + c4;
                    if (ci0 + c4 + 4 <= CsR) v = *(const float4*)gp;
                    else {
                        const int rem = CsR - ci0 - c4;
                        if (rem > 0) { v.x = gp[0]; if (rem > 1) v.y = gp[1]; if (rem > 2) v.z = gp[2]; }
                    }
                }
            }
            stg[it] = v;
        }
    };

    issue(0);
    for (int t = 0; t < NCH; ++t) {
        const unsigned short* __restrict__ Bt = (t < nchx) ? BtX : BtH;
        const int bck = (t < nchx) ? t : t - nchx;
        __syncthreads();           // prev chunk's MFMAs done; stg loads drained
        // ---- COMMIT: cvt + LDS write ----
#pragma unroll
        for (int it = 0; it < ITERS; ++it) {
            const int i = tid + it * 256;
            if (i < NSLOT) {
                const int pix = i >> 3, c4 = (i & 7) << 2;
                us4 hi;
                hi[0] = f2bf(stg[it].x); hi[1] = f2bf(stg[it].y);
                hi[2] = f2bf(stg[it].z); hi[3] = f2bf(stg[it].w);
                *(us4*)(ldsA + pix * PITCH + c4) = hi;
            }
        }
        __syncthreads();           // tile visible
        // ---- prime B tap0 + issue next chunk's A loads (both fly w/ MFMAs) ----
        short8v bcur[NN], bnxt[NN];
#pragma unroll
        for (int nn = 0; nn < NN; ++nn) {
            const int ng = (TILE == 16) ? nn : ((w & 1) * 2 + nn);
            bcur[nn] = *(const short8v*)(Bt +
                ((size_t)((bck * 9) * NG + nb * 4 + ng) << 9) + lane * 8);
        }
        if (t + 1 < NCH) issue(t + 1);
        // ---- 9 taps, register-pipelined B ----
#pragma unroll
        for (int dd = 0; dd < 9; ++dd) {
            if (dd < 8) {
#pragma unroll
                for (int nn = 0; nn < NN; ++nn) {
                    const int ng = (TILE == 16) ? nn : ((w & 1) * 2 + nn);
                    bnxt[nn] = *(const short8v*)(Bt +
                        ((size_t)((bck * 9 + dd + 1) * NG + nb * 4 + ng) << 9) + lane * 8);
                }
            }
            const int dy = dd / 3, dx = dd % 3;
            short8v ah[NFM];
#pragma unroll
            for (int fm = 0; fm < NFM; ++fm) {
                const int ro = (TILE == 16) ? (fm + dy) : (2 * fm + dy);
                ah[fm] = *(const short8v*)(ldsA + abase + (ro * HS + dx) * PITCH);
            }
#pragma unroll
            for (int nn = 0; nn < NN; ++nn)
#pragma unroll
                for (int fm = 0; fm < NFM; ++fm)
                    acc[fm][nn] = __builtin_amdgcn_mfma_f32_16x16x32_bf16(ah[fm], bcur[nn], acc[fm][nn], 0, 0, 0);
            if (dd < 8) {
#pragma unroll
                for (int nn = 0; nn < NN; ++nn) bcur[nn] = bnxt[nn];
            }
        }
    }

    // ---- epilogue: transpose D frags via LDS, apply gates ----
    __syncthreads();
    float* lds2 = (float*)smem + w * 276;    // 16x17 pad, per-wave scratch
    const int rr = lane & 15, cl = lane >> 4;
#pragma unroll
    for (int nn = 0; nn < NN; ++nn) {
        const int ngl = (TILE == 16) ? nn : ((w & 1) * 2 + nn);
        const int c = nb * 16 + ngl * 4 + cl;           // channel in [0,C)
        float b4[4];
#pragma unroll
        for (int g = 0; g < 4; ++g) b4[g] = bias[g * C + c];
#pragma unroll
        for (int fm = 0; fm < NFM; ++fm) {
            // D layout: lane holds col=lane&15, rows (lane>>4)*4+j
#pragma unroll
            for (int j = 0; j < 4; ++j) lds2[(cl * 4 + j) * 17 + rr] = acc[fm][nn][j];
            float z[4];
#pragma unroll
            for (int g = 0; g < 4; ++g) z[g] = lds2[rr * 17 + cl * 4 + g];
            int py, px;
            if (TILE == 16) { py = y0 + w * 4 + fm; px = x0 + rr; }
            else { py = y0 + (w >> 1) * 4 + 2 * fm + (rr >> 3); px = x0 + (rr & 7); }
            const size_t base = ((size_t)py * W + px) * C + c;
            const float cold = hprev ? cst[base] : 0.f;
            const float zi = z[0] + b4[0], zf = z[1] + b4[1];
            const float zc = z[2] + b4[2], zo = z[3] + b4[3];
            const float cn = hsig(zf) * cold + hsig(zi) * fmaxf(zc, 0.f);
            const float hv = hsig(zo) * fmaxf(cn, 0.f);
            cst[base] = cn; hout[base] = hv;
        }
    }
}

// ===== weight pre-transform: fp32 [3][3][Cs][4C] -> fragment-ordered bf16 =====
// layout: [ck][dd][ngrp][lane 0..63][8], k = ck*32+(lane>>4)*8+e,
// co' = ngrp*16 + (lane&15) = c*4+g  ->  src co = g*C + c.  ci>=CsR zero-filled.
// All 28 transforms in ONE launch (job table passed by value).
struct TJob { const float* src; unsigned short* dst; int CsR; int C; int total; };
struct TJobs { TJob j[28]; };

__global__ void transform_all_kernel(TJobs jobs)
{
    const TJob J = jobs.j[blockIdx.y];
    const int i = blockIdx.x * 256 + threadIdx.x;
    if (i >= J.total) return;
    const int N = 4 * J.C, NG = N >> 4;
    const int lane = i & 63; int t = i >> 6;
    const int ng = t % NG; t /= NG;
    const int dd = t % 9; const int ck = t / 9;
    const int colp = ng * 16 + (lane & 15);
    const int c = colp >> 2, g = colp & 3, co = g * J.C + c;
    const int kb = (lane >> 4) * 8;
    short8v hi8;
#pragma unroll
    for (int e = 0; e < 8; ++e) {
        const int ci = (ck << 5) + kb + e;
        const float v = (ci < J.CsR) ? J.src[(size_t)(dd * J.CsR + ci) * N + co] : 0.f;
        hi8[e] = (short)f2bf(v);
    }
    const size_t base = ((size_t)(ck * 9 + dd) * NG + ng) * 512 + lane * 8;
    *(short8v*)(J.dst + base) = hi8;
}

// ---------------- MaxPool (1,2,2), NHWC, float4 over channels ----------------
__global__ void pool_kernel(const float* __restrict__ in, float* __restrict__ out,
                            int H, int Wd, int C, long total4)
{
    const int Ho = H >> 1, Wo = Wd >> 1;
    const int C4 = C >> 2;
    for (long i = (long)blockIdx.x * blockDim.x + threadIdx.x; i < total4;
         i += (long)gridDim.x * blockDim.x) {
        const int c4 = (int)(i % C4);
        long r = i / C4;
        const int x = (int)(r % Wo); r /= Wo;
        const int y = (int)(r % Ho);
        const int t = (int)(r / Ho);
        const float4* a = reinterpret_cast<const float4*>(in) +
                          (((long)t * H + 2 * y) * Wd + 2 * x) * C4 + c4;
        const float4 v00 = a[0], v01 = a[C4];
        const float4 v10 = a[(long)Wd * C4], v11 = a[(long)Wd * C4 + C4];
        float4 o;
        o.x = fmaxf(fmaxf(v00.x, v01.x), fmaxf(v10.x, v11.x));
        o.y = fmaxf(fmaxf(v00.y, v01.y), fmaxf(v10.y, v11.y));
        o.z = fmaxf(fmaxf(v00.z, v01.z), fmaxf(v10.z, v11.z));
        o.w = fmaxf(fmaxf(v00.w, v01.w), fmaxf(v10.w, v11.w));
        reinterpret_cast<float4*>(out)[i] = o;
    }
}

// ------------- concat([A, up2x2(B)], channel-last), float4 -------------
__global__ void upconcat_kernel(const float* __restrict__ A, const float* __restrict__ B,
                                float* __restrict__ out, int H, int Wd, int C1, int C2,
                                long total4)
{
    const int Co4 = (C1 + C2) >> 2, C14 = C1 >> 2, C24 = C2 >> 2;
    for (long i = (long)blockIdx.x * blockDim.x + threadIdx.x; i < total4;
         i += (long)gridDim.x * blockDim.x) {
        const int c4 = (int)(i % Co4);
        long r = i / Co4;
        const int x = (int)(r % Wd); r /= Wd;
        const int y = (int)(r % H);
        const int t = (int)(r / H);
        float4 v;
        if (c4 < C14)
            v = reinterpret_cast<const float4*>(A)[(((long)t * H + y) * Wd + x) * C14 + c4];
        else
            v = reinterpret_cast<const float4*>(B)[
                (((long)t * (H >> 1) + (y >> 1)) * (Wd >> 1) + (x >> 1)) * C24 + (c4 - C14)];
        reinterpret_cast<float4*>(out)[i] = v;
    }
}

// ------------- final 1x1 ConvLSTM, Cin=32 -> C=1 -------------
__global__ void final_step_kernel(const float* __restrict__ h7, const float* __restrict__ hprev,
                                  float* __restrict__ cst, float* __restrict__ hout,
                                  const float* __restrict__ wout,  // [32][4]
                                  const float* __restrict__ uout,  // [4]
                                  const float* __restrict__ bout,  // [4]
                                  float* __restrict__ dout, int N)
{
    const int i = blockIdx.x * 256 + threadIdx.x;
    if (i >= N) return;
    float z0 = bout[0], z1 = bout[1], z2 = bout[2], z3 = bout[3];
    const float* hp = h7 + (size_t)i * 32;
#pragma unroll
    for (int c = 0; c < 32; c += 4) {
        const float4 h4 = *reinterpret_cast<const float4*>(hp + c);
        const float hv4[4] = {h4.x, h4.y, h4.z, h4.w};
#pragma unroll
        for (int j = 0; j < 4; ++j) {
            z0 += hv4[j] * wout[(c + j) * 4 + 0];
            z1 += hv4[j] * wout[(c + j) * 4 + 1];
            z2 += hv4[j] * wout[(c + j) * 4 + 2];
            z3 += hv4[j] * wout[(c + j) * 4 + 3];
        }
    }
    float hpv = 0.f, cold = 0.f;
    if (hprev) { hpv = hprev[i]; cold = cst[i]; }
    z0 += hpv * uout[0]; z1 += hpv * uout[1]; z2 += hpv * uout[2]; z3 += hpv * uout[3];
    const float ig = hsig(z0), fg = hsig(z1), og = hsig(z3);
    const float cd = fmaxf(z2, 0.f);
    const float cn = fg * cold + ig * cd;
    const float hv = og * fmaxf(cn, 0.f);
    cst[i] = cn; hout[i] = hv;
    if (dout) dout[i] = hv;
}

// ---------------- host orchestration ----------------
struct LD { int H, W, CiR, CiP, C, tile, wi; };

static void run_layer(const LD& L, const float* in, float* out, float* cstate,
                      const unsigned short* btx, const unsigned short* bth,
                      const float* bias, hipStream_t stream)
{
    const size_t inS = (size_t)L.H * L.W * L.CiR, outS = (size_t)L.H * L.W * L.C;
    const dim3 grid(L.W / L.tile, L.H / L.tile, (4 * L.C) / 64);
    for (int t = 0; t < T_STEPS; ++t) {
        const float* hp = t ? out + (t - 1) * outS : nullptr;
        if (L.tile == 16) {
            const size_t sh = (size_t)18 * 18 * 40 * 2;   // 25920 B
            lstm_mfma<16><<<grid, 256, sh, stream>>>(in + t * inS, hp, cstate, out + t * outS,
                                                     btx, bth, bias, L.H, L.W, L.CiR, L.CiP, L.C);
        } else {
            const size_t sh = (size_t)10 * 10 * 40 * 2;   // 8000 B
            lstm_mfma<8><<<grid, 256, sh, stream>>>(in + t * inS, hp, cstate, out + t * outS,
                                                    btx, bth, bias, L.H, L.W, L.CiR, L.CiP, L.C);
        }
    }
}

extern "C" void kernel_launch(void* const* d_in, const int* in_sizes, int n_in,
                              void* d_out, int out_size, void* d_ws, size_t ws_size,
                              hipStream_t stream)
{
    (void)in_sizes; (void)n_in; (void)out_size; (void)ws_size;
    const float* x = (const float*)d_in[0];
    auto Wp = [&](int k) { return (const float*)d_in[k]; };
    char* ws = (char*)d_ws;
    const size_t MiB = 1ull << 20;
    auto f = [&](size_t m) { return (float*)(ws + m * MiB); };

    hipFuncSetAttribute((const void*)lstm_mfma<16>,
                        hipFuncAttributeMaxDynamicSharedMemorySize, 26624);
    hipFuncSetAttribute((const void*)lstm_mfma<8>,
                        hipFuncAttributeMaxDynamicSharedMemorySize, 8192);

    // Arena (peak ~210 MiB; lifetimes hand-checked):
    float* bC1  = f(0);    float* bC2  = f(32);  float* bC3  = f(48);
    float* bCST = f(56);   // shared c-state, <= 8 MiB
    float* bHF  = (float*)(ws + 64 * MiB);
    float* bCF  = (float*)(ws + 64 * MiB + 256 * 1024);
    float* bS1A = f(65);   float* bP1  = f(97);  float* bS2A = f(105);
    float* bP2  = f(97);   float* bS3A = f(101); float* bP3  = f(65);
    float* bS4A = f(67);   float* bC4  = f(71);  float* bM5  = f(75);
    float* bS5A = f(99);   float* bC5  = f(65);  float* bM6  = f(73);
    float* bS6A = f(121);  float* bC6  = f(65);  float* bM7  = f(81);
    float* bS7A = f(0);    float* bC7  = f(81);

    static const LD Ls[14] = {
        {256, 256,   1,  32,  32, 16,  1}, {256, 256,  32,  32,  32, 16,  4},
        {128, 128,  32,  32,  64,  8,  7}, {128, 128,  64,  64,  64,  8, 10},
        { 64,  64,  64,  64, 128,  8, 13}, { 64,  64, 128, 128, 128,  8, 16},
        { 32,  32, 128, 128, 256,  8, 19}, { 32,  32, 256, 256, 256,  8, 22},
        { 64,  64, 384, 384, 128,  8, 25}, { 64,  64, 128, 128, 128,  8, 28},
        {128, 128, 192, 192,  64,  8, 31}, {128, 128,  64,  64,  64,  8, 34},
        {256, 256,  96,  96,  32, 16, 37}, {256, 256,  32,  32,  32, 16, 40},
    };

    // ---- weight transforms into Bt arena at [177 MiB, ...), ONE launch ----
    unsigned short* btx[14]; unsigned short* bth[14];
    {
        TJobs jobs;
        int maxTotal = 0;
        size_t cur = 177 * MiB;
        for (int i = 0; i < 14; ++i) {
            const LD& L = Ls[i];
            const int NG = (4 * L.C) >> 4;
            const size_t szx = (size_t)(L.CiP >> 5) * 9 * NG * 1024;  // bytes
            const size_t szh = (size_t)(L.C  >> 5) * 9 * NG * 1024;
            btx[i] = (unsigned short*)(ws + cur); cur += szx;
            bth[i] = (unsigned short*)(ws + cur); cur += szh;
            const int totx = (L.CiP >> 5) * 9 * NG * 64;
            const int toth = (L.C  >> 5) * 9 * NG * 64;
            jobs.j[2 * i]     = {Wp(L.wi),     btx[i], L.CiR, L.C, totx};
            jobs.j[2 * i + 1] = {Wp(L.wi + 1), bth[i], L.C,   L.C, toth};
            if (totx > maxTotal) maxTotal = totx;
            if (toth > maxTotal) maxTotal = toth;
        }
        transform_all_kernel<<<dim3((maxTotal + 255) / 256, 28), 256, 0, stream>>>(jobs);
    }

    auto pool = [&](const float* in, float* out, int H, int Wd, int C) {
        long total4 = (long)T_STEPS * (H / 2) * (Wd / 2) * (C / 4);
        long nb = (total4 + 255) / 256; if (nb > 4096) nb = 4096;
        pool_kernel<<<dim3((unsigned)nb), 256, 0, stream>>>(in, out, H, Wd, C, total4);
    };
    auto upcat = [&](const float* A, const float* B, float* out, int H, int Wd, int C1, int C2) {
        long total4 = (long)T_STEPS * H * Wd * ((C1 + C2) / 4);
        long nb = (total4 + 255) / 256; if (nb > 8192) nb = 8192;
        upconcat_kernel<<<dim3((unsigned)nb), 256, 0, stream>>>(A, B, out, H, Wd, C1, C2, total4);
    };
    auto run = [&](int i, const float* in, float* out) {
        run_layer(Ls[i], in, out, bCST, btx[i], bth[i], Wp(Ls[i].wi + 2), stream);
    };

    run(0, x, bS1A);        run(1, bS1A, bC1);
    pool(bC1, bP1, 256, 256, 32);
    run(2, bP1, bS2A);      run(3, bS2A, bC2);
    pool(bC2, bP2, 128, 128, 64);
    run(4, bP2, bS3A);      run(5, bS3A, bC3);
    pool(bC3, bP3, 64, 64, 128);
    run(6, bP3, bS4A);      run(7, bS4A, bC4);
    upcat(bC3, bC4, bM5, 64, 64, 128, 256);
    run(8, bM5, bS5A);      run(9, bS5A, bC5);
    upcat(bC2, bC5, bM6, 128, 128, 64, 128);
    run(10, bM6, bS6A);     run(11, bS6A, bC6);
    upcat(bC1, bC6, bM7, 256, 256, 32, 64);
    run(12, bM7, bS7A);     run(13, bS7A, bC7);

    const int N = 256 * 256;
    for (int t = 0; t < T_STEPS; ++t) {
        const float* h7 = bC7 + (size_t)t * N * 32;
        final_step_kernel<<<N / 256, 256, 0, stream>>>(
            h7, t ? bHF : nullptr, bCF, bHF, Wp(43), Wp(44), Wp(45),
            (t == T_STEPS - 1) ? (float*)d_out : nullptr, N);
    }
}